// Round 9
// baseline (117.978 us; speedup 1.0000x reference)
//
#include <hip/hip_runtime.h>
#include <hip/hip_bf16.h>

#define HEADS 16
#define SEQ   4096
#define DIM   64
#define QT    64
#define KT    64
#define SCALE 0.125f
// SCALE * log2(e): folded into Q at conversion so scores are in log2 domain
#define CF    0.18033688011112042f
#define LOG2E 1.4426950408889634f

typedef __bf16 v8bf  __attribute__((ext_vector_type(8)));
typedef __bf16 v4bf  __attribute__((ext_vector_type(4)));
typedef float  f32x4 __attribute__((ext_vector_type(4)));

__device__ __forceinline__ __bf16 to_bf(float f) { return (__bf16)f; }
// v_exp_f32 computes 2^x; v_log_f32 computes log2(x)
__device__ __forceinline__ float ex2(float x) { return __builtin_amdgcn_exp2f(x); }
__device__ __forceinline__ float lg2(float x) { return __builtin_amdgcn_logf(x); }

__device__ __forceinline__ void gload16(const __bf16* g, __bf16* l) {
    __builtin_amdgcn_global_load_lds(
        (const __attribute__((address_space(1))) void*)g,
        (__attribute__((address_space(3))) void*)l,
        16, 0, 0);
}

// ===========================================================================
// Pre-pass: convert fp32 -> bf16; fold CF into Q; transpose K,V.
// V columns additionally permuted (within each 64-key tile) so the PV
// B-operand needs zero cross-lane redistribution.
// ===========================================================================
__global__ __launch_bounds__(256) void conv_q_kernel(
    const float* __restrict__ qg, __bf16* __restrict__ Qb)
{
    size_t i = ((size_t)blockIdx.x * 256 + threadIdx.x) * 8;
    float4 f0 = *(const float4*)(qg + i);
    float4 f1 = *(const float4*)(qg + i + 4);
    v8bf o;
    o[0] = to_bf(f0.x * CF); o[1] = to_bf(f0.y * CF);
    o[2] = to_bf(f0.z * CF); o[3] = to_bf(f0.w * CF);
    o[4] = to_bf(f1.x * CF); o[5] = to_bf(f1.y * CF);
    o[6] = to_bf(f1.z * CF); o[7] = to_bf(f1.w * CF);
    *(v8bf*)(Qb + i) = o;
}

// z=0: K [h][d][s] -> Kb [h][t][d];  z=1: V [h][s][d] -> Vb [h][d][perm(t)]
__global__ __launch_bounds__(256) void conv_kv_kernel(
    const float* __restrict__ kg, const float* __restrict__ vg,
    __bf16* __restrict__ Kb, __bf16* __restrict__ Vb)
{
    __shared__ __bf16 ldsT[64][65];
    const int h   = blockIdx.y;
    const int t0  = blockIdx.x * 64;
    const int tid = threadIdx.x;
    const int rr  = tid >> 2;          // 0..63
    const int cq  = (tid & 3) * 16;    // 0,16,32,48

    if (blockIdx.z == 0) {
        const float* src = kg + ((size_t)h * DIM + rr) * SEQ + t0 + cq;  // d=rr
        #pragma unroll
        for (int j = 0; j < 4; ++j) {
            float4 f = *(const float4*)(src + 4 * j);
            ldsT[rr][cq + 4 * j + 0] = to_bf(f.x);
            ldsT[rr][cq + 4 * j + 1] = to_bf(f.y);
            ldsT[rr][cq + 4 * j + 2] = to_bf(f.z);
            ldsT[rr][cq + 4 * j + 3] = to_bf(f.w);
        }
        __syncthreads();
        __bf16* dst = Kb + (size_t)h * SEQ * DIM + (size_t)(t0 + rr) * DIM + cq;
        v8bf o0, o1;
        #pragma unroll
        for (int i = 0; i < 8; ++i) {
            o0[i] = ldsT[cq + i][rr];       // ldsT[t][d] -> Kb[t][d]
            o1[i] = ldsT[cq + 8 + i][rr];
        }
        *(v8bf*)dst = o0;
        *(v8bf*)(dst + 8) = o1;
    } else {
        const float* src = vg + ((size_t)h * SEQ + t0 + rr) * DIM + cq;  // t=rr
        #pragma unroll
        for (int j = 0; j < 4; ++j) {
            float4 f = *(const float4*)(src + 4 * j);
            ldsT[rr][cq + 4 * j + 0] = to_bf(f.x);
            ldsT[rr][cq + 4 * j + 1] = to_bf(f.y);
            ldsT[rr][cq + 4 * j + 2] = to_bf(f.z);
            ldsT[rr][cq + 4 * j + 3] = to_bf(f.w);
        }
        __syncthreads();
        // values val[i] = V[key=t0+cq+i][d=rr]; within-tile key kt = cq+i.
        __bf16* dst0 = Vb + ((size_t)h * DIM + rr) * SEQ + t0;
        const int n  = cq >> 4;                    // fixed per lane
        const int c0 = 32 * (n >> 1) + 4 * (n & 1);
        #pragma unroll
        for (int j2 = 0; j2 < 4; ++j2) {
            v4bf ch;
            #pragma unroll
            for (int r = 0; r < 4; ++r)
                ch[r] = ldsT[cq + 4 * j2 + r][rr];
            *(v4bf*)(dst0 + c0 + 8 * j2) = ch;
        }
    }
}

// ===========================================================================
// Pass A v9: swapped QK^T, no-max softmax, key-permuted V, XCD head pinning,
// qtile pairing (bq, 63-bq) for perfect balance (grid 512, 2 blocks/CU),
// ring-3 LDS buffers with COUNTED vmcnt (T4): per tile, wait own loads
// (vmcnt(4)) BEFORE a raw s_barrier (so all waves' chunks are staged), then
// issue tile t+2's loads (buffer freed by the barrier). Loads are waited
// two compute-phases after issue -> zero drain stall.
// ===========================================================================
__global__ __launch_bounds__(256, 2) void fa_fwd4_kernel(
    const __bf16* __restrict__ Qb, const __bf16* __restrict__ Kb,
    const __bf16* __restrict__ Vb, float* __restrict__ outg,
    float* __restrict__ lseg)
{
    const int b    = blockIdx.x;
    const int xcd  = b & 7;
    const int j    = b >> 3;           // 0..63
    const int h    = 2 * xcd + (j & 1);
    const int bq   = j >> 1;           // 0..31 (qtile pair index)
    const int tid  = threadIdx.x;
    const int wave = tid >> 6;
    const int lane = tid & 63;
    const int g    = lane >> 4;
    const int l16  = lane & 15;

    __shared__ alignas(16) __bf16 ldsK[3][KT * DIM];   // ring of 3
    __shared__ alignas(16) __bf16 ldsV[3][DIM * KT];

    // staging: thread covers 16B at linear tile byte tid*16 (+4096);
    // source column pre-XOR'd so LDS ends up in swizzled layout
    const int r0 = tid >> 3;           // 0..31
    const int c0 = tid & 7;
    const size_t kOff0 = (size_t)r0 * DIM + (size_t)((c0 ^ (r0 & 7)) << 3);
    const size_t kOff1 = (size_t)(r0 + 32) * DIM + (size_t)((c0 ^ ((r0 + 32) & 7)) << 3);
    const size_t vOff0 = (size_t)r0 * SEQ + (size_t)((c0 ^ (r0 & 7)) << 3);
    const size_t vOff1 = (size_t)(r0 + 32) * SEQ + (size_t)((c0 ^ ((r0 + 32) & 7)) << 3);
    const __bf16* KbH = Kb + (size_t)h * SEQ * DIM;
    const __bf16* VbH = Vb + (size_t)h * DIM * SEQ;
    const int ldsW = wave * 512;       // per-wave element base within 4KB half

    #pragma unroll 1
    for (int pi = 0; pi < 2; ++pi) {
        const int qtile = pi ? (63 - bq) : bq;
        const int qw = qtile * QT + wave * 16;
        const int nt = qtile + 1;
        const int q  = qw + l16;       // this lane's query row

        // Q fragment (B operand): col j = l16 (q), k = kk*32 + g*8 + e
        const __bf16* qrow = Qb + ((size_t)h * SEQ + q) * DIM + g * 8;
        v8bf aq0 = *(const v8bf*)qrow;
        v8bf aq1 = *(const v8bf*)(qrow + 32);

        // acc[n][r] = O^T[d = 16n+4g+r][q];  lp = partial l for q
        f32x4 acc[4];
        #pragma unroll
        for (int n = 0; n < 4; ++n) acc[n] = (f32x4){0.f, 0.f, 0.f, 0.f};
        float lp[4] = {0.f, 0.f, 0.f, 0.f};

        // prologue: stage tiles 0 and (if present) 1 into ring slots 0,1
        {
            gload16(KbH + kOff0, &ldsK[0][ldsW]);
            gload16(KbH + kOff1, &ldsK[0][2048 + ldsW]);
            gload16(VbH + vOff0, &ldsV[0][ldsW]);
            gload16(VbH + vOff1, &ldsV[0][2048 + ldsW]);
            if (nt > 1) {
                const __bf16* kb = KbH + (size_t)KT * DIM;
                const __bf16* vb = VbH + KT;
                gload16(kb + kOff0, &ldsK[1][ldsW]);
                gload16(kb + kOff1, &ldsK[1][2048 + ldsW]);
                gload16(vb + vOff0, &ldsV[1][ldsW]);
                gload16(vb + vOff1, &ldsV[1][2048 + ldsW]);
            }
        }

        int bi = 0;   // compute buffer for tile t
        int si = 2;   // staging buffer for tile t+2

        #pragma unroll 1
        for (int t = 0; t < nt; ++t) {
            // wait for OWN tile-t loads (tile t+1's 4 stay in flight)
            if (t + 1 < nt) {
                asm volatile("s_waitcnt vmcnt(4)" ::: "memory");
            } else {
                asm volatile("s_waitcnt vmcnt(0)" ::: "memory");
            }
            __builtin_amdgcn_sched_barrier(0);
            __builtin_amdgcn_s_barrier();   // all waves' tile-t chunks staged;
                                            // all waves done computing t-1
            __builtin_amdgcn_sched_barrier(0);
            // issue tile t+2's staging into the buffer freed by the barrier
            if (t + 2 < nt) {
                const __bf16* kb = KbH + (size_t)(t + 2) * KT * DIM;
                const __bf16* vb = VbH + (size_t)(t + 2) * KT;
                gload16(kb + kOff0, &ldsK[si][ldsW]);
                gload16(kb + kOff1, &ldsK[si][2048 + ldsW]);
                gload16(vb + vOff0, &ldsV[si][ldsW]);
                gload16(vb + vOff1, &ldsV[si][2048 + ldsW]);
            }
            // ---- QK^T swapped: s[n][r] = S^T[key = 64t+16n+4g+r][q]
            f32x4 s[4];
            #pragma unroll
            for (int n = 0; n < 4; ++n) s[n] = (f32x4){0.f, 0.f, 0.f, 0.f};
            __builtin_amdgcn_s_setprio(1);
            #pragma unroll
            for (int kk = 0; kk < 2; ++kk) {
                #pragma unroll
                for (int n = 0; n < 4; ++n) {
                    int row  = 16 * n + l16;
                    int byte = row * 128 + kk * 64 + g * 16;
                    byte ^= (row & 7) << 4;
                    v8bf ak = *(const v8bf*)&ldsK[bi][byte >> 1];
                    s[n] = __builtin_amdgcn_mfma_f32_16x16x32_bf16(
                        ak, kk ? aq1 : aq0, s[n], 0, 0, 0);
                }
            }
            __builtin_amdgcn_s_setprio(0);
            // ---- causal mask: only the diagonal tile
            if (t == nt - 1) {
                const int qit = wave * 16 + l16;    // q within tile
                #pragma unroll
                for (int n = 0; n < 4; ++n)
                    #pragma unroll
                    for (int r2 = 0; r2 < 4; ++r2)
                        if (16 * n + 4 * g + r2 > qit) s[n][r2] = -3.0e38f;
            }
            // ---- p = exp2(s) (no max subtraction; scores bounded), pack to
            //      B-fragments for permuted-V PV. Zero cross-lane ops.
            v8bf pa0, pa1;
            #pragma unroll
            for (int n = 0; n < 4; ++n) {
                #pragma unroll
                for (int r2 = 0; r2 < 4; ++r2) {
                    float p = ex2(s[n][r2]);
                    lp[r2] += p;
                    if (n < 2) pa0[(n & 1) * 4 + r2] = to_bf(p);
                    else       pa1[(n & 1) * 4 + r2] = to_bf(p);
                }
            }
            // ---- PV: acc[n] = O^T slice, A = V^T rows from permuted ldsV
            __builtin_amdgcn_s_setprio(1);
            #pragma unroll
            for (int kk = 0; kk < 2; ++kk) {
                #pragma unroll
                for (int n = 0; n < 4; ++n) {
                    int row  = 16 * n + l16;
                    int byte = row * 128 + kk * 64 + g * 16;
                    byte ^= (row & 7) << 4;
                    v8bf av = *(const v8bf*)&ldsV[bi][byte >> 1];
                    acc[n] = __builtin_amdgcn_mfma_f32_16x16x32_bf16(
                        av, kk ? pa1 : pa0, acc[n], 0, 0, 0);
                }
            }
            __builtin_amdgcn_s_setprio(0);
            bi = (bi == 2) ? 0 : bi + 1;
            si = (si == 2) ? 0 : si + 1;
        }
        // end-of-qtile barrier: protect ring reuse by pi=1's prologue
        __builtin_amdgcn_s_barrier();

        // ---- epilogue: l reduce across the 4 g-lanes of this q, store
        float l = (lp[0] + lp[1]) + (lp[2] + lp[3]);
        l += __shfl_xor(l, 16);
        l += __shfl_xor(l, 32);
        const float inv = 1.0f / l;
        float* orow = outg + ((size_t)h * SEQ + q) * DIM;
        #pragma unroll
        for (int n = 0; n < 4; ++n) {
            f32x4 o = acc[n];
            o[0] *= inv; o[1] *= inv; o[2] *= inv; o[3] *= inv;
            *(f32x4*)(orow + 16 * n + 4 * g) = o;
        }
        if (g == 0)
            lseg[h * SEQ + q] = lg2(l);
    }
}

// ===========================================================================
// Pass B v3: row_sum[t] = sum_q exp2(s_qt - lse2_q). Key-tile pairing
// (ta, 63-ta) + q-range split into two balanced halves (grid 1024,
// 4 blocks/CU). Halves write partials; rs_add combines.
// ===========================================================================
__global__ __launch_bounds__(256, 4) void fa_colsum2_kernel(
    const __bf16* __restrict__ Qb, const __bf16* __restrict__ Kb,
    const float* __restrict__ lseg, float* __restrict__ partg)
{
    const int b    = blockIdx.x;
    const int xcd  = b & 7;
    const int j    = b >> 3;            // 0..127
    const int h    = 2 * xcd + (j & 1);
    const int m    = j >> 1;            // 0..63
    const int ta   = m & 31;
    const int half = m >> 5;
    const int tb   = 63 - ta;
    const int smid = (ta <= 15) ? (ta + 33) : 48;
    const int qlo  = half ? smid : ta;
    const int qhiE = half ? 64 : smid;
    const int tid  = threadIdx.x;
    const int wave = tid >> 6;
    const int lane = tid & 63;
    const int g    = lane >> 4;
    const int l16  = lane & 15;

    __shared__ alignas(16) __bf16 ldsK2[2][KT * DIM];
    __shared__ float cs[2][4][KT];

    const int r0 = tid >> 3;
    const int c0 = tid & 7;
    const size_t kOff0 = (size_t)r0 * DIM + (size_t)((c0 ^ (r0 & 7)) << 3);
    const size_t kOff1 = (size_t)(r0 + 32) * DIM + (size_t)((c0 ^ ((r0 + 32) & 7)) << 3);
    const __bf16* KbH = Kb + (size_t)h * SEQ * DIM;
    const int ldsW = wave * 512;

    gload16(KbH + (size_t)ta * KT * DIM + kOff0, &ldsK2[0][ldsW]);
    gload16(KbH + (size_t)ta * KT * DIM + kOff1, &ldsK2[0][2048 + ldsW]);
    gload16(KbH + (size_t)tb * KT * DIM + kOff0, &ldsK2[1][ldsW]);
    gload16(KbH + (size_t)tb * KT * DIM + kOff1, &ldsK2[1][2048 + ldsW]);
    __syncthreads();

    float accA[4] = {0.f, 0.f, 0.f, 0.f};
    float accB[4] = {0.f, 0.f, 0.f, 0.f};

    #pragma unroll 1
    for (int qt = qlo; qt < qhiE; ++qt) {
        const int qw = qt * QT + wave * 16;
        const __bf16* qrow = Qb + ((size_t)h * SEQ + qw + l16) * DIM + g * 8;
        v8bf aq0 = *(const v8bf*)qrow;
        v8bf aq1 = *(const v8bf*)(qrow + 32);
        float4 lse4 = *(const float4*)(lseg + (size_t)h * SEQ + qw + 4 * g);

        // ---- tile A (active for all qt in range; qt >= ta by construction)
        {
            f32x4 s[4];
            #pragma unroll
            for (int n = 0; n < 4; ++n) s[n] = (f32x4){0.f, 0.f, 0.f, 0.f};
            __builtin_amdgcn_s_setprio(1);
            #pragma unroll
            for (int kk = 0; kk < 2; ++kk)
                #pragma unroll
                for (int n = 0; n < 4; ++n) {
                    int row  = 16 * n + l16;
                    int byte = row * 128 + kk * 64 + g * 16;
                    byte ^= (row & 7) << 4;
                    v8bf bk = *(const v8bf*)&ldsK2[0][byte >> 1];
                    s[n] = __builtin_amdgcn_mfma_f32_16x16x32_bf16(
                        kk ? aq1 : aq0, bk, s[n], 0, 0, 0);
                }
            __builtin_amdgcn_s_setprio(0);
            if (qt == ta) {
                #pragma unroll
                for (int n = 0; n < 4; ++n) {
                    const int key = ta * KT + 16 * n + l16;
                    #pragma unroll
                    for (int r2 = 0; r2 < 4; ++r2) {
                        float e = ex2(s[n][r2] - lse4[r2]);
                        accA[n] += (key <= qw + 4 * g + r2) ? e : 0.f;
                    }
                }
            } else {
                #pragma unroll
                for (int n = 0; n < 4; ++n)
                    #pragma unroll
                    for (int r2 = 0; r2 < 4; ++r2)
                        accA[n] += ex2(s[n][r2] - lse4[r2]);
            }
        }
        // ---- tile B (active for qt >= tb)
        if (qt >= tb) {
            f32x4 s[4];
            #pragma unroll
            for (int n = 0; n < 4; ++n) s[n] = (f32x4){0.f, 0.f, 0.f, 0.f};
            __builtin_amdgcn_s_setprio(1);
            #pragma unroll
            for (int kk = 0; kk < 2; ++kk)
                #pragma unroll
                for (int n = 0; n < 4; ++n) {
                    int row  = 16 * n + l16;
                    int byte = row * 128 + kk * 64 + g * 16;
                    byte ^= (row & 7) << 4;
                    v8bf bk = *(const v8bf*)&ldsK2[1][byte >> 1];
                    s[n] = __builtin_amdgcn_mfma_f32_16x16x32_bf16(
                        kk ? aq1 : aq0, bk, s[n], 0, 0, 0);
                }
            __builtin_amdgcn_s_setprio(0);
            if (qt == tb) {
                #pragma unroll
                for (int n = 0; n < 4; ++n) {
                    const int key = tb * KT + 16 * n + l16;
                    #pragma unroll
                    for (int r2 = 0; r2 < 4; ++r2) {
                        float e = ex2(s[n][r2] - lse4[r2]);
                        accB[n] += (key <= qw + 4 * g + r2) ? e : 0.f;
                    }
                }
            } else {
                #pragma unroll
                for (int n = 0; n < 4; ++n)
                    #pragma unroll
                    for (int r2 = 0; r2 < 4; ++r2)
                        accB[n] += ex2(s[n][r2] - lse4[r2]);
            }
        }
    }

    #pragma unroll
    for (int n = 0; n < 4; ++n) {
        accA[n] += __shfl_xor(accA[n], 16);
        accA[n] += __shfl_xor(accA[n], 32);
        accB[n] += __shfl_xor(accB[n], 16);
        accB[n] += __shfl_xor(accB[n], 32);
    }
    if (lane < 16) {
        #pragma unroll
        for (int n = 0; n < 4; ++n) {
            cs[0][wave][16 * n + lane] = accA[n];
            cs[1][wave][16 * n + lane] = accB[n];
        }
    }
    __syncthreads();
    float* pg = partg + (size_t)half * HEADS * SEQ + (size_t)h * SEQ;
    if (tid < KT) {
        pg[ta * KT + tid] =
            cs[0][0][tid] + cs[0][1][tid] + cs[0][2][tid] + cs[0][3][tid];
    } else if (tid < 2 * KT) {
        const int t = tid - KT;
        pg[tb * KT + t] =
            cs[1][0][t] + cs[1][1][t] + cs[1][2][t] + cs[1][3][t];
    }
}

// combine the two partial halves into row_sum
__global__ __launch_bounds__(256) void rs_add_kernel(
    const float* __restrict__ partg, float* __restrict__ rsg)
{
    const int i = blockIdx.x * 256 + threadIdx.x;       // 16384 float4s
    f32x4 x = *(const f32x4*)(partg + (size_t)i * 4);
    f32x4 y = *(const f32x4*)(partg + (size_t)HEADS * SEQ + (size_t)i * 4);
    x[0] += y[0]; x[1] += y[1]; x[2] += y[2]; x[3] += y[3];
    *(f32x4*)(rsg + (size_t)i * 4) = x;
}

// ===========================================================================
// Fallback (round-1, fp32 inputs, scalar staging) — used if ws too small.
// ===========================================================================
__global__ __launch_bounds__(256, 1) void fa_fwd_v1_kernel(
    const float* __restrict__ qg, const float* __restrict__ kg,
    const float* __restrict__ vg, float* __restrict__ outg,
    float* __restrict__ lseg)
{
    const int h    = blockIdx.y;
    const int q0   = blockIdx.x * QT;
    const int tid  = threadIdx.x;
    const int wave = tid >> 6;
    const int lane = tid & 63;
    const int g    = lane >> 4;
    const int l16  = lane & 15;

    __shared__ alignas(16) __bf16 ldsK[KT * DIM];
    __shared__ alignas(16) __bf16 ldsV[DIM * KT];
    __shared__ alignas(16) __bf16 ldsP[4][16 * 72];

    const int qw = q0 + wave * 16;
    v8bf aq[2];
    {
        const float* qrow = qg + ((size_t)h * SEQ + qw + l16) * DIM;
        #pragma unroll
        for (int kk = 0; kk < 2; ++kk) {
            const float* p = qrow + kk * 32 + g * 8;
            float4 f0 = *(const float4*)p;
            float4 f1 = *(const float4*)(p + 4);
            aq[kk][0] = to_bf(f0.x); aq[kk][1] = to_bf(f0.y);
            aq[kk][2] = to_bf(f0.z); aq[kk][3] = to_bf(f0.w);
            aq[kk][4] = to_bf(f1.x); aq[kk][5] = to_bf(f1.y);
            aq[kk][6] = to_bf(f1.z); aq[kk][7] = to_bf(f1.w);
        }
    }
    f32x4 acc[4];
    #pragma unroll
    for (int n = 0; n < 4; ++n) acc[n] = (f32x4){0.f, 0.f, 0.f, 0.f};
    float m_r[4], l_r[4];
    #pragma unroll
    for (int r = 0; r < 4; ++r) { m_r[r] = -__builtin_inff(); l_r[r] = 0.f; }

    const int ntiles = q0 / KT + 1;
    const int kd = tid >> 2;
    const int kc = (tid & 3) * 16;

    for (int t = 0; t < ntiles; ++t) {
        const int t0 = t * KT;
        __syncthreads();
        {
            const float* src = kg + ((size_t)h * DIM + kd) * SEQ + t0 + kc;
            #pragma unroll
            for (int j = 0; j < 4; ++j) {
                float4 f = *(const float4*)(src + 4 * j);
                #pragma unroll
                for (int i = 0; i < 4; ++i) {
                    int row  = kc + 4 * j + i;
                    int byte = row * 128 + kd * 2;
                    byte ^= (row & 7) << 4;
                    ldsK[byte >> 1] = to_bf(((const float*)&f)[i]);
                }
            }
        }
        {
            const float* src = vg + ((size_t)h * SEQ + t0 + kd) * DIM + kc;
            #pragma unroll
            for (int j = 0; j < 4; ++j) {
                float4 f = *(const float4*)(src + 4 * j);
                #pragma unroll
                for (int i = 0; i < 4; ++i) {
                    int row  = kc + 4 * j + i;
                    int byte = row * 128 + kd * 2;
                    byte ^= (row & 7) << 4;
                    ldsV[byte >> 1] = to_bf(((const float*)&f)[i]);
                }
            }
        }
        __syncthreads();

        f32x4 s[4];
        #pragma unroll
        for (int n = 0; n < 4; ++n) s[n] = (f32x4){0.f, 0.f, 0.f, 0.f};
        #pragma unroll
        for (int kk = 0; kk < 2; ++kk)
            #pragma unroll
            for (int n = 0; n < 4; ++n) {
                int row  = 16 * n + l16;
                int byte = row * 128 + kk * 64 + g * 16;
                byte ^= (row & 7) << 4;
                v8bf bk = *(const v8bf*)&ldsK[byte >> 1];
                s[n] = __builtin_amdgcn_mfma_f32_16x16x32_bf16(aq[kk], bk, s[n], 0, 0, 0);
            }
        float pvv[4][4];
        #pragma unroll
        for (int r = 0; r < 4; ++r) {
            const int qq = qw + 4 * g + r;
            float sv[4];
            #pragma unroll
            for (int n = 0; n < 4; ++n) {
                int key = t0 + 16 * n + l16;
                sv[n] = (key <= qq) ? s[n][r] * (SCALE * LOG2E) : -3.0e38f;
            }
            float mx = fmaxf(fmaxf(sv[0], sv[1]), fmaxf(sv[2], sv[3]));
            mx = fmaxf(mx, __shfl_xor(mx, 1));
            mx = fmaxf(mx, __shfl_xor(mx, 2));
            mx = fmaxf(mx, __shfl_xor(mx, 4));
            mx = fmaxf(mx, __shfl_xor(mx, 8));
            float mnew = fmaxf(m_r[r], mx);
            float corr = ex2(m_r[r] - mnew);
            m_r[r] = mnew;
            float rs = 0.f;
            #pragma unroll
            for (int n = 0; n < 4; ++n) {
                float p = (sv[n] > -1.0e38f) ? ex2(sv[n] - mnew) : 0.f;
                pvv[n][r] = p;
                rs += p;
            }
            rs += __shfl_xor(rs, 1);
            rs += __shfl_xor(rs, 2);
            rs += __shfl_xor(rs, 4);
            rs += __shfl_xor(rs, 8);
            l_r[r] = l_r[r] * corr + rs;
            #pragma unroll
            for (int n = 0; n < 4; ++n) acc[n][r] *= corr;
        }
        #pragma unroll
        for (int n = 0; n < 4; ++n)
            #pragma unroll
            for (int r = 0; r < 4; ++r)
                ldsP[wave][(4 * g + r) * 72 + 16 * n + l16] = to_bf(pvv[n][r]);
        asm volatile("s_waitcnt lgkmcnt(0)" ::: "memory");
        __builtin_amdgcn_sched_barrier(0);
        #pragma unroll
        for (int kk = 0; kk < 2; ++kk) {
            v8bf ap = *(const v8bf*)&ldsP[wave][l16 * 72 + 32 * kk + 8 * g];
            #pragma unroll
            for (int n = 0; n < 4; ++n) {
                int row  = 16 * n + l16;
                int byte = row * 128 + kk * 64 + g * 16;
                byte ^= (row & 7) << 4;
                v8bf bv = *(const v8bf*)&ldsV[byte >> 1];
                acc[n] = __builtin_amdgcn_mfma_f32_16x16x32_bf16(ap, bv, acc[n], 0, 0, 0);
            }
        }
    }
    #pragma unroll
    for (int r = 0; r < 4; ++r) {
        const int qq  = qw + 4 * g + r;
        const float inv = 1.0f / l_r[r];
        float* orow = outg + ((size_t)h * SEQ + qq) * DIM;
        #pragma unroll
        for (int n = 0; n < 4; ++n)
            orow[16 * n + l16] = acc[n][r] * inv;
        if (l16 == 0)
            lseg[h * SEQ + qq] = m_r[r] + lg2(l_r[r]);
    }
}

__global__ __launch_bounds__(256, 1) void fa_colsum_v1_kernel(
    const float* __restrict__ qg, const float* __restrict__ kg,
    const float* __restrict__ lseg, float* __restrict__ rsg)
{
    const int h    = blockIdx.y;
    const int t0   = blockIdx.x * KT;
    const int tid  = threadIdx.x;
    const int wave = tid >> 6;
    const int lane = tid & 63;
    const int g    = lane >> 4;
    const int l16  = lane & 15;

    __shared__ alignas(16) __bf16 ldsK[KT * DIM];
    __shared__ float cs[4][KT];
    {
        const int kd = tid >> 2;
        const int kc = (tid & 3) * 16;
        const float* src = kg + ((size_t)h * DIM + kd) * SEQ + t0 + kc;
        #pragma unroll
        for (int j = 0; j < 4; ++j) {
            float4 f = *(const float4*)(src + 4 * j);
            #pragma unroll
            for (int i = 0; i < 4; ++i) {
                int row  = kc + 4 * j + i;
                int byte = row * 128 + kd * 2;
                byte ^= (row & 7) << 4;
                ldsK[byte >> 1] = to_bf(((const float*)&f)[i]);
            }
        }
    }
    __syncthreads();
    float colacc[4] = {0.f, 0.f, 0.f, 0.f};
    for (int qt = t0 / QT; qt < SEQ / QT; ++qt) {
        const int qw = qt * QT + wave * 16;
        const float* qrow = qg + ((size_t)h * SEQ + qw + l16) * DIM;
        v8bf aq[2];
        #pragma unroll
        for (int kk = 0; kk < 2; ++kk) {
            const float* p = qrow + kk * 32 + g * 8;
            float4 f0 = *(const float4*)p;
            float4 f1 = *(const float4*)(p + 4);
            aq[kk][0] = to_bf(f0.x); aq[kk][1] = to_bf(f0.y);
            aq[kk][2] = to_bf(f0.z); aq[kk][3] = to_bf(f0.w);
            aq[kk][4] = to_bf(f1.x); aq[kk][5] = to_bf(f1.y);
            aq[kk][6] = to_bf(f1.z); aq[kk][7] = to_bf(f1.w);
        }
        float lse_r[4];
        #pragma unroll
        for (int r = 0; r < 4; ++r)
            lse_r[r] = lseg[h * SEQ + qw + 4 * g + r];
        f32x4 s[4];
        #pragma unroll
        for (int n = 0; n < 4; ++n) s[n] = (f32x4){0.f, 0.f, 0.f, 0.f};
        #pragma unroll
        for (int kk = 0; kk < 2; ++kk)
            #pragma unroll
            for (int n = 0; n < 4; ++n) {
                int row  = 16 * n + l16;
                int byte = row * 128 + kk * 64 + g * 16;
                byte ^= (row & 7) << 4;
                v8bf bk = *(const v8bf*)&ldsK[byte >> 1];
                s[n] = __builtin_amdgcn_mfma_f32_16x16x32_bf16(aq[kk], bk, s[n], 0, 0, 0);
            }
        #pragma unroll
        for (int n = 0; n < 4; ++n) {
            const int key = t0 + 16 * n + l16;
            #pragma unroll
            for (int r = 0; r < 4; ++r) {
                const int qq = qw + 4 * g + r;
                if (key <= qq)
                    colacc[n] += ex2(s[n][r] * (SCALE * LOG2E) - lse_r[r]);
            }
        }
    }
    #pragma unroll
    for (int n = 0; n < 4; ++n) {
        colacc[n] += __shfl_xor(colacc[n], 16);
        colacc[n] += __shfl_xor(colacc[n], 32);
    }
    if (lane < 16) {
        #pragma unroll
        for (int n = 0; n < 4; ++n)
            cs[wave][16 * n + lane] = colacc[n];
    }
    __syncthreads();
    if (tid < KT) {
        float v = cs[0][tid] + cs[1][tid] + cs[2][tid] + cs[3][tid];
        rsg[h * SEQ + t0 + tid] = v;
    }
}

extern "C" void kernel_launch(void* const* d_in, const int* in_sizes, int n_in,
                              void* d_out, int out_size, void* d_ws, size_t ws_size,
                              hipStream_t stream) {
    (void)in_sizes; (void)n_in; (void)out_size;
    const float* qg = (const float*)d_in[0];
    const float* kg = (const float*)d_in[1];
    const float* vg = (const float*)d_in[2];
    float* outg = (float*)d_out;
    float* rsg  = outg + (size_t)HEADS * SEQ * DIM;

    const size_t nElem   = (size_t)HEADS * SEQ * DIM;        // 4.19M
    const size_t lseB    = (size_t)HEADS * SEQ * sizeof(float);
    const size_t needB   = lseB + 3 * nElem * sizeof(__bf16);

    if (ws_size >= needB) {
        float*  lseg = (float*)d_ws;
        __bf16* Qb = (__bf16*)((char*)d_ws + lseB);
        __bf16* Kb = Qb + nElem;
        __bf16* Vb = Kb + nElem;
        // colsum partials overlay Vb (dead after fwd); 512KB << Vb's 8.4MB
        float* partg = (float*)Vb;
        conv_q_kernel<<<dim3((int)(nElem / 2048)), 256, 0, stream>>>(qg, Qb);
        conv_kv_kernel<<<dim3(SEQ / 64, HEADS, 2), 256, 0, stream>>>(kg, vg, Kb, Vb);
        fa_fwd4_kernel<<<dim3(512), 256, 0, stream>>>(Qb, Kb, Vb, outg, lseg);
        fa_colsum2_kernel<<<dim3(1024), 256, 0, stream>>>(Qb, Kb, lseg, partg);
        rs_add_kernel<<<dim3(HEADS * SEQ / 1024), 256, 0, stream>>>(partg, rsg);
    } else {
        float* lseg = (float*)d_ws;
        dim3 grid(SEQ / QT, HEADS);
        fa_fwd_v1_kernel<<<grid, 256, 0, stream>>>(qg, kg, vg, outg, lseg);
        fa_colsum_v1_kernel<<<grid, 256, 0, stream>>>(qg, kg, lseg, rsg);
    }
}

// Round 10
// 99.989 us; speedup vs baseline: 1.1799x; 1.1799x over previous
//
#include <hip/hip_runtime.h>
#include <hip/hip_bf16.h>

#define HEADS 16
#define SEQ   4096
#define DIM   64
#define QT    64
#define KT    64
#define SCALE 0.125f
// SCALE * log2(e): folded into Q at conversion so scores are in log2 domain
#define CF    0.18033688011112042f
#define LOG2E 1.4426950408889634f

typedef __bf16 v8bf  __attribute__((ext_vector_type(8)));
typedef __bf16 v4bf  __attribute__((ext_vector_type(4)));
typedef float  f32x4 __attribute__((ext_vector_type(4)));

__device__ __forceinline__ __bf16 to_bf(float f) { return (__bf16)f; }
// v_exp_f32 computes 2^x; v_log_f32 computes log2(x)
__device__ __forceinline__ float ex2(float x) { return __builtin_amdgcn_exp2f(x); }
__device__ __forceinline__ float lg2(float x) { return __builtin_amdgcn_logf(x); }

__device__ __forceinline__ void gload16(const __bf16* g, __bf16* l) {
    __builtin_amdgcn_global_load_lds(
        (const __attribute__((address_space(1))) void*)g,
        (__attribute__((address_space(3))) void*)l,
        16, 0, 0);
}

// ===========================================================================
// Fused pre-pass (one launch): z=0 K [h][d][s] -> Kb [h][t][d];
// z=1 V [h][s][d] -> Vb [h][d][perm(t)] (perm makes PV B-operand in-lane);
// z=2 Q scale-convert (CF folded).
// ===========================================================================
__global__ __launch_bounds__(256) void conv_fused_kernel(
    const float* __restrict__ qg, const float* __restrict__ kg,
    const float* __restrict__ vg, __bf16* __restrict__ Qb,
    __bf16* __restrict__ Kb, __bf16* __restrict__ Vb)
{
    __shared__ __bf16 ldsT[64][65];
    const int h   = blockIdx.y;
    const int t0  = blockIdx.x * 64;
    const int tid = threadIdx.x;
    const int rr  = tid >> 2;          // 0..63
    const int cq  = (tid & 3) * 16;    // 0,16,32,48

    if (blockIdx.z == 2) {
        // Q: straight scale-convert, row t0+rr, cols cq..cq+15
        const float* src = qg + ((size_t)h * SEQ + t0 + rr) * DIM + cq;
        __bf16* dst = Qb + ((size_t)h * SEQ + t0 + rr) * DIM + cq;
        v8bf o0, o1;
        #pragma unroll
        for (int j = 0; j < 2; ++j) {
            float4 f0 = *(const float4*)(src + 8 * j);
            float4 f1 = *(const float4*)(src + 8 * j + 4);
            v8bf o;
            o[0] = to_bf(f0.x * CF); o[1] = to_bf(f0.y * CF);
            o[2] = to_bf(f0.z * CF); o[3] = to_bf(f0.w * CF);
            o[4] = to_bf(f1.x * CF); o[5] = to_bf(f1.y * CF);
            o[6] = to_bf(f1.z * CF); o[7] = to_bf(f1.w * CF);
            if (j == 0) o0 = o; else o1 = o;
        }
        *(v8bf*)dst = o0;
        *(v8bf*)(dst + 8) = o1;
        return;
    }

    if (blockIdx.z == 0) {
        const float* src = kg + ((size_t)h * DIM + rr) * SEQ + t0 + cq;  // d=rr
        #pragma unroll
        for (int j = 0; j < 4; ++j) {
            float4 f = *(const float4*)(src + 4 * j);
            ldsT[rr][cq + 4 * j + 0] = to_bf(f.x);
            ldsT[rr][cq + 4 * j + 1] = to_bf(f.y);
            ldsT[rr][cq + 4 * j + 2] = to_bf(f.z);
            ldsT[rr][cq + 4 * j + 3] = to_bf(f.w);
        }
        __syncthreads();
        __bf16* dst = Kb + (size_t)h * SEQ * DIM + (size_t)(t0 + rr) * DIM + cq;
        v8bf o0, o1;
        #pragma unroll
        for (int i = 0; i < 8; ++i) {
            o0[i] = ldsT[cq + i][rr];       // ldsT[t][d] -> Kb[t][d]
            o1[i] = ldsT[cq + 8 + i][rr];
        }
        *(v8bf*)dst = o0;
        *(v8bf*)(dst + 8) = o1;
    } else {
        const float* src = vg + ((size_t)h * SEQ + t0 + rr) * DIM + cq;  // t=rr
        #pragma unroll
        for (int j = 0; j < 4; ++j) {
            float4 f = *(const float4*)(src + 4 * j);
            ldsT[rr][cq + 4 * j + 0] = to_bf(f.x);
            ldsT[rr][cq + 4 * j + 1] = to_bf(f.y);
            ldsT[rr][cq + 4 * j + 2] = to_bf(f.z);
            ldsT[rr][cq + 4 * j + 3] = to_bf(f.w);
        }
        __syncthreads();
        // values val[i] = V[key=t0+cq+i][d=rr]; within-tile key kt = cq+i.
        __bf16* dst0 = Vb + ((size_t)h * DIM + rr) * SEQ + t0;
        const int n  = cq >> 4;                    // fixed per lane
        const int c0 = 32 * (n >> 1) + 4 * (n & 1);
        #pragma unroll
        for (int j2 = 0; j2 < 4; ++j2) {
            v4bf ch;
            #pragma unroll
            for (int r = 0; r < 4; ++r)
                ch[r] = ldsT[cq + 4 * j2 + r][rr];
            *(v4bf*)(dst0 + c0 + 8 * j2) = ch;
        }
    }
}

// ===========================================================================
// Pass A (round-7 best, 60.7us measured): swapped QK^T, no-max softmax,
// key-permuted V, XCD head pinning, 128-key double-subtile iterations,
// fused qtile pair (a, 63-a): K/V staged once, each ds_read feeds 2 MFMAs,
// constant per-block work.
// ===========================================================================
__global__ __launch_bounds__(256, 2) void fa_fwd2_kernel(
    const __bf16* __restrict__ Qb, const __bf16* __restrict__ Kb,
    const __bf16* __restrict__ Vb, float* __restrict__ outg,
    float* __restrict__ lseg)
{
    const int b    = blockIdx.x;
    const int xcd  = b & 7;
    const int j    = b >> 3;           // 0..63
    const int h    = 2 * xcd + (j & 1);
    const int a    = j >> 1;           // 0..31: qtile pair (a, 63-a)
    const int tid  = threadIdx.x;
    const int wave = tid >> 6;
    const int lane = tid & 63;
    const int g    = lane >> 4;
    const int l16  = lane & 15;
    const int wit  = wave * 16 + l16;  // q-row within its qtile

    const int na  = a + 1;             // tiles for lo qtile
    const int nb  = 64 - a;            // tiles for hi qtile
    const int nIt = (nb + 1) >> 1;     // 128-key iterations

    __shared__ alignas(16) __bf16 ldsK[2][2][KT * DIM];   // [buf][sub]
    __shared__ alignas(16) __bf16 ldsV[2][2][DIM * KT];

    const int r0 = tid >> 3;           // 0..31
    const int c0 = tid & 7;
    const size_t kOff0 = (size_t)r0 * DIM + (size_t)((c0 ^ (r0 & 7)) << 3);
    const size_t kOff1 = (size_t)(r0 + 32) * DIM + (size_t)((c0 ^ ((r0 + 32) & 7)) << 3);
    const size_t vOff0 = (size_t)r0 * SEQ + (size_t)((c0 ^ (r0 & 7)) << 3);
    const size_t vOff1 = (size_t)(r0 + 32) * SEQ + (size_t)((c0 ^ ((r0 + 32) & 7)) << 3);
    const __bf16* KbH = Kb + (size_t)h * SEQ * DIM;
    const __bf16* VbH = Vb + (size_t)h * DIM * SEQ;
    const int ldsW = wave * 512;       // per-wave element base within 4KB half

    const int qlo = a * QT + wit;           // lo q row
    const int qhi = (63 - a) * QT + wit;    // hi q row

    const __bf16* qlr = Qb + ((size_t)h * SEQ + qlo) * DIM + g * 8;
    const __bf16* qhr = Qb + ((size_t)h * SEQ + qhi) * DIM + g * 8;
    v8bf aqlo0 = *(const v8bf*)qlr;
    v8bf aqlo1 = *(const v8bf*)(qlr + 32);
    v8bf aqhi0 = *(const v8bf*)qhr;
    v8bf aqhi1 = *(const v8bf*)(qhr + 32);

    f32x4 accl[4], acch[4];
    #pragma unroll
    for (int n = 0; n < 4; ++n) {
        accl[n] = (f32x4){0.f, 0.f, 0.f, 0.f};
        acch[n] = (f32x4){0.f, 0.f, 0.f, 0.f};
    }
    float lpl[4] = {0.f, 0.f, 0.f, 0.f};
    float lph[4] = {0.f, 0.f, 0.f, 0.f};

    int cur = 0;
    // prologue: stage tiles 0,1 (always in-range: nb >= 33)
    #pragma unroll
    for (int u = 0; u < 2; ++u) {
        const __bf16* kb = KbH + (size_t)(64 * u) * DIM;
        const __bf16* vb = VbH + 64 * u;
        gload16(kb + kOff0, &ldsK[0][u][ldsW]);
        gload16(kb + kOff1, &ldsK[0][u][2048 + ldsW]);
        gload16(vb + vOff0, &ldsV[0][u][ldsW]);
        gload16(vb + vOff1, &ldsV[0][u][2048 + ldsW]);
    }
    __syncthreads();

    auto sub_full = [&](int u, int t) {
        f32x4 sl[4], sh[4];
        #pragma unroll
        for (int n = 0; n < 4; ++n) {
            sl[n] = (f32x4){0.f, 0.f, 0.f, 0.f};
            sh[n] = (f32x4){0.f, 0.f, 0.f, 0.f};
        }
        __builtin_amdgcn_s_setprio(1);
        #pragma unroll
        for (int kk = 0; kk < 2; ++kk) {
            #pragma unroll
            for (int n = 0; n < 4; ++n) {
                int row  = 16 * n + l16;
                int byte = row * 128 + kk * 64 + g * 16;
                byte ^= (row & 7) << 4;
                v8bf ak = *(const v8bf*)&ldsK[cur][u][byte >> 1];
                sl[n] = __builtin_amdgcn_mfma_f32_16x16x32_bf16(
                    ak, kk ? aqlo1 : aqlo0, sl[n], 0, 0, 0);
                sh[n] = __builtin_amdgcn_mfma_f32_16x16x32_bf16(
                    ak, kk ? aqhi1 : aqhi0, sh[n], 0, 0, 0);
            }
        }
        __builtin_amdgcn_s_setprio(0);
        if (t >= na - 1) {              // lo diag / overflow tile (uniform)
            const int lim = (a - t) * 64 + wit;
            #pragma unroll
            for (int n = 0; n < 4; ++n)
                #pragma unroll
                for (int r = 0; r < 4; ++r)
                    if (16 * n + 4 * g + r > lim) sl[n][r] = -3.0e38f;
        }
        v8bf pl0, pl1, ph0, ph1;
        #pragma unroll
        for (int n = 0; n < 4; ++n) {
            #pragma unroll
            for (int r = 0; r < 4; ++r) {
                float p = ex2(sl[n][r]);
                float q = ex2(sh[n][r]);
                lpl[r] += p;
                lph[r] += q;
                if (n < 2) { pl0[(n & 1) * 4 + r] = to_bf(p);
                             ph0[(n & 1) * 4 + r] = to_bf(q); }
                else       { pl1[(n & 1) * 4 + r] = to_bf(p);
                             ph1[(n & 1) * 4 + r] = to_bf(q); }
            }
        }
        __builtin_amdgcn_s_setprio(1);
        #pragma unroll
        for (int kk = 0; kk < 2; ++kk) {
            #pragma unroll
            for (int n = 0; n < 4; ++n) {
                int row  = 16 * n + l16;
                int byte = row * 128 + kk * 64 + g * 16;
                byte ^= (row & 7) << 4;
                v8bf av = *(const v8bf*)&ldsV[cur][u][byte >> 1];
                accl[n] = __builtin_amdgcn_mfma_f32_16x16x32_bf16(
                    av, kk ? pl1 : pl0, accl[n], 0, 0, 0);
                acch[n] = __builtin_amdgcn_mfma_f32_16x16x32_bf16(
                    av, kk ? ph1 : ph0, acch[n], 0, 0, 0);
            }
        }
        __builtin_amdgcn_s_setprio(0);
    };

    auto sub_hi = [&](int u, int t) {
        f32x4 sh[4];
        #pragma unroll
        for (int n = 0; n < 4; ++n) sh[n] = (f32x4){0.f, 0.f, 0.f, 0.f};
        __builtin_amdgcn_s_setprio(1);
        #pragma unroll
        for (int kk = 0; kk < 2; ++kk) {
            #pragma unroll
            for (int n = 0; n < 4; ++n) {
                int row  = 16 * n + l16;
                int byte = row * 128 + kk * 64 + g * 16;
                byte ^= (row & 7) << 4;
                v8bf ak = *(const v8bf*)&ldsK[cur][u][byte >> 1];
                sh[n] = __builtin_amdgcn_mfma_f32_16x16x32_bf16(
                    ak, kk ? aqhi1 : aqhi0, sh[n], 0, 0, 0);
            }
        }
        __builtin_amdgcn_s_setprio(0);
        if (t >= nb - 1) {              // hi diag / overflow tile (uniform)
            const int lim = (63 - a - t) * 64 + wit;
            #pragma unroll
            for (int n = 0; n < 4; ++n)
                #pragma unroll
                for (int r = 0; r < 4; ++r)
                    if (16 * n + 4 * g + r > lim) sh[n][r] = -3.0e38f;
        }
        v8bf ph0, ph1;
        #pragma unroll
        for (int n = 0; n < 4; ++n) {
            #pragma unroll
            for (int r = 0; r < 4; ++r) {
                float q = ex2(sh[n][r]);
                lph[r] += q;
                if (n < 2) ph0[(n & 1) * 4 + r] = to_bf(q);
                else       ph1[(n & 1) * 4 + r] = to_bf(q);
            }
        }
        __builtin_amdgcn_s_setprio(1);
        #pragma unroll
        for (int kk = 0; kk < 2; ++kk) {
            #pragma unroll
            for (int n = 0; n < 4; ++n) {
                int row  = 16 * n + l16;
                int byte = row * 128 + kk * 64 + g * 16;
                byte ^= (row & 7) << 4;
                v8bf av = *(const v8bf*)&ldsV[cur][u][byte >> 1];
                acch[n] = __builtin_amdgcn_mfma_f32_16x16x32_bf16(
                    av, kk ? ph1 : ph0, acch[n], 0, 0, 0);
            }
        }
        __builtin_amdgcn_s_setprio(0);
    };

    #pragma unroll 1
    for (int it = 0; it < nIt; ++it) {
        if (it + 1 < nIt) {            // stage next 128-key pair
            #pragma unroll
            for (int u = 0; u < 2; ++u) {
                const __bf16* kb = KbH + (size_t)(128 * (it + 1) + 64 * u) * DIM;
                const __bf16* vb = VbH + 128 * (it + 1) + 64 * u;
                gload16(kb + kOff0, &ldsK[cur ^ 1][u][ldsW]);
                gload16(kb + kOff1, &ldsK[cur ^ 1][u][2048 + ldsW]);
                gload16(vb + vOff0, &ldsV[cur ^ 1][u][ldsW]);
                gload16(vb + vOff1, &ldsV[cur ^ 1][u][2048 + ldsW]);
            }
        }
        const int t0 = 2 * it;
        if (t0 < na) { sub_full(0, t0); sub_full(1, t0 + 1); }
        else         { sub_hi(0, t0);   sub_hi(1, t0 + 1);   }
        __syncthreads();   // drains vmcnt: next pair ready; this one free
        cur ^= 1;
    }

    // ---- epilogue: per-group l reduce across the 4 g-lanes, store
    {
        float l = (lpl[0] + lpl[1]) + (lpl[2] + lpl[3]);
        l += __shfl_xor(l, 16);
        l += __shfl_xor(l, 32);
        const float inv = 1.0f / l;
        float* orow = outg + ((size_t)h * SEQ + qlo) * DIM;
        #pragma unroll
        for (int n = 0; n < 4; ++n) {
            f32x4 o = accl[n];
            o[0] *= inv; o[1] *= inv; o[2] *= inv; o[3] *= inv;
            *(f32x4*)(orow + 16 * n + 4 * g) = o;
        }
        if (g == 0) lseg[h * SEQ + qlo] = lg2(l);
    }
    {
        float l = (lph[0] + lph[1]) + (lph[2] + lph[3]);
        l += __shfl_xor(l, 16);
        l += __shfl_xor(l, 32);
        const float inv = 1.0f / l;
        float* orow = outg + ((size_t)h * SEQ + qhi) * DIM;
        #pragma unroll
        for (int n = 0; n < 4; ++n) {
            f32x4 o = acch[n];
            o[0] *= inv; o[1] *= inv; o[2] *= inv; o[3] *= inv;
            *(f32x4*)(orow + 16 * n + 4 * g) = o;
        }
        if (g == 0) lseg[h * SEQ + qhi] = lg2(l);
    }
}

// ===========================================================================
// Pass B (round-6 best): row_sum[t] = sum_q exp2(s_qt - lse2_q).
// Key-tile pairing (ta, 63-ta), XCD head pinning, grid 512, writes rsg.
// ===========================================================================
__global__ __launch_bounds__(256, 2) void fa_colsum2_kernel(
    const __bf16* __restrict__ Qb, const __bf16* __restrict__ Kb,
    const float* __restrict__ lseg, float* __restrict__ rsg)
{
    const int b    = blockIdx.x;
    const int xcd  = b & 7;
    const int j    = b >> 3;
    const int h    = 2 * xcd + (j & 1);
    const int ta   = j >> 1;            // 0..31
    const int tb   = 63 - ta;
    const int tid  = threadIdx.x;
    const int wave = tid >> 6;
    const int lane = tid & 63;
    const int g    = lane >> 4;
    const int l16  = lane & 15;

    __shared__ alignas(16) __bf16 ldsK2[2][KT * DIM];
    __shared__ float cs[2][4][KT];

    const int r0 = tid >> 3;
    const int c0 = tid & 7;
    const size_t kOff0 = (size_t)r0 * DIM + (size_t)((c0 ^ (r0 & 7)) << 3);
    const size_t kOff1 = (size_t)(r0 + 32) * DIM + (size_t)((c0 ^ ((r0 + 32) & 7)) << 3);
    const __bf16* KbH = Kb + (size_t)h * SEQ * DIM;
    const int ldsW = wave * 512;

    gload16(KbH + (size_t)ta * KT * DIM + kOff0, &ldsK2[0][ldsW]);
    gload16(KbH + (size_t)ta * KT * DIM + kOff1, &ldsK2[0][2048 + ldsW]);
    gload16(KbH + (size_t)tb * KT * DIM + kOff0, &ldsK2[1][ldsW]);
    gload16(KbH + (size_t)tb * KT * DIM + kOff1, &ldsK2[1][2048 + ldsW]);
    __syncthreads();

    float accA[4] = {0.f, 0.f, 0.f, 0.f};
    float accB[4] = {0.f, 0.f, 0.f, 0.f};

    #pragma unroll 1
    for (int qt = ta; qt < SEQ / QT; ++qt) {
        const int qw = qt * QT + wave * 16;
        const __bf16* qrow = Qb + ((size_t)h * SEQ + qw + l16) * DIM + g * 8;
        v8bf aq0 = *(const v8bf*)qrow;
        v8bf aq1 = *(const v8bf*)(qrow + 32);
        float4 lse4 = *(const float4*)(lseg + (size_t)h * SEQ + qw + 4 * g);

        // ---- tile A (always active for qt >= ta)
        {
            f32x4 s[4];
            #pragma unroll
            for (int n = 0; n < 4; ++n) s[n] = (f32x4){0.f, 0.f, 0.f, 0.f};
            __builtin_amdgcn_s_setprio(1);
            #pragma unroll
            for (int kk = 0; kk < 2; ++kk)
                #pragma unroll
                for (int n = 0; n < 4; ++n) {
                    int row  = 16 * n + l16;
                    int byte = row * 128 + kk * 64 + g * 16;
                    byte ^= (row & 7) << 4;
                    v8bf bk = *(const v8bf*)&ldsK2[0][byte >> 1];
                    s[n] = __builtin_amdgcn_mfma_f32_16x16x32_bf16(
                        kk ? aq1 : aq0, bk, s[n], 0, 0, 0);
                }
            __builtin_amdgcn_s_setprio(0);
            if (qt == ta) {
                #pragma unroll
                for (int n = 0; n < 4; ++n) {
                    const int key = ta * KT + 16 * n + l16;
                    #pragma unroll
                    for (int r = 0; r < 4; ++r) {
                        float e = ex2(s[n][r] - lse4[r]);
                        accA[n] += (key <= qw + 4 * g + r) ? e : 0.f;
                    }
                }
            } else {
                #pragma unroll
                for (int n = 0; n < 4; ++n)
                    #pragma unroll
                    for (int r = 0; r < 4; ++r)
                        accA[n] += ex2(s[n][r] - lse4[r]);
            }
        }
        // ---- tile B (active for qt >= tb)
        if (qt >= tb) {
            f32x4 s[4];
            #pragma unroll
            for (int n = 0; n < 4; ++n) s[n] = (f32x4){0.f, 0.f, 0.f, 0.f};
            __builtin_amdgcn_s_setprio(1);
            #pragma unroll
            for (int kk = 0; kk < 2; ++kk)
                #pragma unroll
                for (int n = 0; n < 4; ++n) {
                    int row  = 16 * n + l16;
                    int byte = row * 128 + kk * 64 + g * 16;
                    byte ^= (row & 7) << 4;
                    v8bf bk = *(const v8bf*)&ldsK2[1][byte >> 1];
                    s[n] = __builtin_amdgcn_mfma_f32_16x16x32_bf16(
                        kk ? aq1 : aq0, bk, s[n], 0, 0, 0);
                }
            __builtin_amdgcn_s_setprio(0);
            if (qt == tb) {
                #pragma unroll
                for (int n = 0; n < 4; ++n) {
                    const int key = tb * KT + 16 * n + l16;
                    #pragma unroll
                    for (int r = 0; r < 4; ++r) {
                        float e = ex2(s[n][r] - lse4[r]);
                        accB[n] += (key <= qw + 4 * g + r) ? e : 0.f;
                    }
                }
            } else {
                #pragma unroll
                for (int n = 0; n < 4; ++n)
                    #pragma unroll
                    for (int r = 0; r < 4; ++r)
                        accB[n] += ex2(s[n][r] - lse4[r]);
            }
        }
    }

    #pragma unroll
    for (int n = 0; n < 4; ++n) {
        accA[n] += __shfl_xor(accA[n], 16);
        accA[n] += __shfl_xor(accA[n], 32);
        accB[n] += __shfl_xor(accB[n], 16);
        accB[n] += __shfl_xor(accB[n], 32);
    }
    if (lane < 16) {
        #pragma unroll
        for (int n = 0; n < 4; ++n) {
            cs[0][wave][16 * n + lane] = accA[n];
            cs[1][wave][16 * n + lane] = accB[n];
        }
    }
    __syncthreads();
    if (tid < KT) {
        rsg[(size_t)h * SEQ + ta * KT + tid] =
            cs[0][0][tid] + cs[0][1][tid] + cs[0][2][tid] + cs[0][3][tid];
    } else if (tid < 2 * KT) {
        const int t = tid - KT;
        rsg[(size_t)h * SEQ + tb * KT + t] =
            cs[1][0][t] + cs[1][1][t] + cs[1][2][t] + cs[1][3][t];
    }
}

// ===========================================================================
// Fallback (round-1, fp32 inputs, scalar staging) — used if ws too small.
// ===========================================================================
__global__ __launch_bounds__(256, 1) void fa_fwd_v1_kernel(
    const float* __restrict__ qg, const float* __restrict__ kg,
    const float* __restrict__ vg, float* __restrict__ outg,
    float* __restrict__ lseg)
{
    const int h    = blockIdx.y;
    const int q0   = blockIdx.x * QT;
    const int tid  = threadIdx.x;
    const int wave = tid >> 6;
    const int lane = tid & 63;
    const int g    = lane >> 4;
    const int l16  = lane & 15;

    __shared__ alignas(16) __bf16 ldsK[KT * DIM];
    __shared__ alignas(16) __bf16 ldsV[DIM * KT];
    __shared__ alignas(16) __bf16 ldsP[4][16 * 72];

    const int qw = q0 + wave * 16;
    v8bf aq[2];
    {
        const float* qrow = qg + ((size_t)h * SEQ + qw + l16) * DIM;
        #pragma unroll
        for (int kk = 0; kk < 2; ++kk) {
            const float* p = qrow + kk * 32 + g * 8;
            float4 f0 = *(const float4*)p;
            float4 f1 = *(const float4*)(p + 4);
            aq[kk][0] = to_bf(f0.x); aq[kk][1] = to_bf(f0.y);
            aq[kk][2] = to_bf(f0.z); aq[kk][3] = to_bf(f0.w);
            aq[kk][4] = to_bf(f1.x); aq[kk][5] = to_bf(f1.y);
            aq[kk][6] = to_bf(f1.z); aq[kk][7] = to_bf(f1.w);
        }
    }
    f32x4 acc[4];
    #pragma unroll
    for (int n = 0; n < 4; ++n) acc[n] = (f32x4){0.f, 0.f, 0.f, 0.f};
    float m_r[4], l_r[4];
    #pragma unroll
    for (int r = 0; r < 4; ++r) { m_r[r] = -__builtin_inff(); l_r[r] = 0.f; }

    const int ntiles = q0 / KT + 1;
    const int kd = tid >> 2;
    const int kc = (tid & 3) * 16;

    for (int t = 0; t < ntiles; ++t) {
        const int t0 = t * KT;
        __syncthreads();
        {
            const float* src = kg + ((size_t)h * DIM + kd) * SEQ + t0 + kc;
            #pragma unroll
            for (int j = 0; j < 4; ++j) {
                float4 f = *(const float4*)(src + 4 * j);
                #pragma unroll
                for (int i = 0; i < 4; ++i) {
                    int row  = kc + 4 * j + i;
                    int byte = row * 128 + kd * 2;
                    byte ^= (row & 7) << 4;
                    ldsK[byte >> 1] = to_bf(((const float*)&f)[i]);
                }
            }
        }
        {
            const float* src = vg + ((size_t)h * SEQ + t0 + kd) * DIM + kc;
            #pragma unroll
            for (int j = 0; j < 4; ++j) {
                float4 f = *(const float4*)(src + 4 * j);
                #pragma unroll
                for (int i = 0; i < 4; ++i) {
                    int row  = kc + 4 * j + i;
                    int byte = row * 128 + kd * 2;
                    byte ^= (row & 7) << 4;
                    ldsV[byte >> 1] = to_bf(((const float*)&f)[i]);
                }
            }
        }
        __syncthreads();

        f32x4 s[4];
        #pragma unroll
        for (int n = 0; n < 4; ++n) s[n] = (f32x4){0.f, 0.f, 0.f, 0.f};
        #pragma unroll
        for (int kk = 0; kk < 2; ++kk)
            #pragma unroll
            for (int n = 0; n < 4; ++n) {
                int row  = 16 * n + l16;
                int byte = row * 128 + kk * 64 + g * 16;
                byte ^= (row & 7) << 4;
                v8bf bk = *(const v8bf*)&ldsK[byte >> 1];
                s[n] = __builtin_amdgcn_mfma_f32_16x16x32_bf16(aq[kk], bk, s[n], 0, 0, 0);
            }
        float pvv[4][4];
        #pragma unroll
        for (int r = 0; r < 4; ++r) {
            const int qq = qw + 4 * g + r;
            float sv[4];
            #pragma unroll
            for (int n = 0; n < 4; ++n) {
                int key = t0 + 16 * n + l16;
                sv[n] = (key <= qq) ? s[n][r] * (SCALE * LOG2E) : -3.0e38f;
            }
            float mx = fmaxf(fmaxf(sv[0], sv[1]), fmaxf(sv[2], sv[3]));
            mx = fmaxf(mx, __shfl_xor(mx, 1));
            mx = fmaxf(mx, __shfl_xor(mx, 2));
            mx = fmaxf(mx, __shfl_xor(mx, 4));
            mx = fmaxf(mx, __shfl_xor(mx, 8));
            float mnew = fmaxf(m_r[r], mx);
            float corr = ex2(m_r[r] - mnew);
            m_r[r] = mnew;
            float rs = 0.f;
            #pragma unroll
            for (int n = 0; n < 4; ++n) {
                float p = (sv[n] > -1.0e38f) ? ex2(sv[n] - mnew) : 0.f;
                pvv[n][r] = p;
                rs += p;
            }
            rs += __shfl_xor(rs, 1);
            rs += __shfl_xor(rs, 2);
            rs += __shfl_xor(rs, 4);
            rs += __shfl_xor(rs, 8);
            l_r[r] = l_r[r] * corr + rs;
            #pragma unroll
            for (int n = 0; n < 4; ++n) acc[n][r] *= corr;
        }
        #pragma unroll
        for (int n = 0; n < 4; ++n)
            #pragma unroll
            for (int r = 0; r < 4; ++r)
                ldsP[wave][(4 * g + r) * 72 + 16 * n + l16] = to_bf(pvv[n][r]);
        asm volatile("s_waitcnt lgkmcnt(0)" ::: "memory");
        __builtin_amdgcn_sched_barrier(0);
        #pragma unroll
        for (int kk = 0; kk < 2; ++kk) {
            v8bf ap = *(const v8bf*)&ldsP[wave][l16 * 72 + 32 * kk + 8 * g];
            #pragma unroll
            for (int n = 0; n < 4; ++n) {
                int row  = 16 * n + l16;
                int byte = row * 128 + kk * 64 + g * 16;
                byte ^= (row & 7) << 4;
                v8bf bv = *(const v8bf*)&ldsV[byte >> 1];
                acc[n] = __builtin_amdgcn_mfma_f32_16x16x32_bf16(ap, bv, acc[n], 0, 0, 0);
            }
        }
    }
    #pragma unroll
    for (int r = 0; r < 4; ++r) {
        const int qq  = qw + 4 * g + r;
        const float inv = 1.0f / l_r[r];
        float* orow = outg + ((size_t)h * SEQ + qq) * DIM;
        #pragma unroll
        for (int n = 0; n < 4; ++n)
            orow[16 * n + l16] = acc[n][r] * inv;
        if (l16 == 0)
            lseg[h * SEQ + qq] = m_r[r] + lg2(l_r[r]);
    }
}

__global__ __launch_bounds__(256, 1) void fa_colsum_v1_kernel(
    const float* __restrict__ qg, const float* __restrict__ kg,
    const float* __restrict__ lseg, float* __restrict__ rsg)
{
    const int h    = blockIdx.y;
    const int t0   = blockIdx.x * KT;
    const int tid  = threadIdx.x;
    const int wave = tid >> 6;
    const int lane = tid & 63;
    const int g    = lane >> 4;
    const int l16  = lane & 15;

    __shared__ alignas(16) __bf16 ldsK[KT * DIM];
    __shared__ float cs[4][KT];
    {
        const int kd = tid >> 2;
        const int kc = (tid & 3) * 16;
        const float* src = kg + ((size_t)h * DIM + kd) * SEQ + t0 + kc;
        #pragma unroll
        for (int j = 0; j < 4; ++j) {
            float4 f = *(const float4*)(src + 4 * j);
            #pragma unroll
            for (int i = 0; i < 4; ++i) {
                int row  = kc + 4 * j + i;
                int byte = row * 128 + kd * 2;
                byte ^= (row & 7) << 4;
                ldsK[byte >> 1] = to_bf(((const float*)&f)[i]);
            }
        }
    }
    __syncthreads();
    float colacc[4] = {0.f, 0.f, 0.f, 0.f};
    for (int qt = t0 / QT; qt < SEQ / QT; ++qt) {
        const int qw = qt * QT + wave * 16;
        const float* qrow = qg + ((size_t)h * SEQ + qw + l16) * DIM;
        v8bf aq[2];
        #pragma unroll
        for (int kk = 0; kk < 2; ++kk) {
            const float* p = qrow + kk * 32 + g * 8;
            float4 f0 = *(const float4*)p;
            float4 f1 = *(const float4*)(p + 4);
            aq[kk][0] = to_bf(f0.x); aq[kk][1] = to_bf(f0.y);
            aq[kk][2] = to_bf(f0.z); aq[kk][3] = to_bf(f0.w);
            aq[kk][4] = to_bf(f1.x); aq[kk][5] = to_bf(f1.y);
            aq[kk][6] = to_bf(f1.z); aq[kk][7] = to_bf(f1.w);
        }
        float lse_r[4];
        #pragma unroll
        for (int r = 0; r < 4; ++r)
            lse_r[r] = lseg[h * SEQ + qw + 4 * g + r];
        f32x4 s[4];
        #pragma unroll
        for (int n = 0; n < 4; ++n) s[n] = (f32x4){0.f, 0.f, 0.f, 0.f};
        #pragma unroll
        for (int kk = 0; kk < 2; ++kk)
            #pragma unroll
            for (int n = 0; n < 4; ++n) {
                int row  = 16 * n + l16;
                int byte = row * 128 + kk * 64 + g * 16;
                byte ^= (row & 7) << 4;
                v8bf bk = *(const v8bf*)&ldsK[byte >> 1];
                s[n] = __builtin_amdgcn_mfma_f32_16x16x32_bf16(aq[kk], bk, s[n], 0, 0, 0);
            }
        #pragma unroll
        for (int n = 0; n < 4; ++n) {
            const int key = t0 + 16 * n + l16;
            #pragma unroll
            for (int r = 0; r < 4; ++r) {
                const int qq = qw + 4 * g + r;
                if (key <= qq)
                    colacc[n] += ex2(s[n][r] * (SCALE * LOG2E) - lse_r[r]);
            }
        }
    }
    #pragma unroll
    for (int n = 0; n < 4; ++n) {
        colacc[n] += __shfl_xor(colacc[n], 16);
        colacc[n] += __shfl_xor(colacc[n], 32);
    }
    if (lane < 16) {
        #pragma unroll
        for (int n = 0; n < 4; ++n)
            cs[wave][16 * n + lane] = colacc[n];
    }
    __syncthreads();
    if (tid < KT) {
        float v = cs[0][tid] + cs[1][tid] + cs[2][tid] + cs[3][tid];
        rsg[h * SEQ + t0 + tid] = v;
    }
}

extern "C" void kernel_launch(void* const* d_in, const int* in_sizes, int n_in,
                              void* d_out, int out_size, void* d_ws, size_t ws_size,
                              hipStream_t stream) {
    (void)in_sizes; (void)n_in; (void)out_size;
    const float* qg = (const float*)d_in[0];
    const float* kg = (const float*)d_in[1];
    const float* vg = (const float*)d_in[2];
    float* outg = (float*)d_out;
    float* rsg  = outg + (size_t)HEADS * SEQ * DIM;

    const size_t nElem   = (size_t)HEADS * SEQ * DIM;        // 4.19M
    const size_t lseB    = (size_t)HEADS * SEQ * sizeof(float);
    const size_t needB   = lseB + 3 * nElem * sizeof(__bf16);

    if (ws_size >= needB) {
        float*  lseg = (float*)d_ws;
        __bf16* Qb = (__bf16*)((char*)d_ws + lseB);
        __bf16* Kb = Qb + nElem;
        __bf16* Vb = Kb + nElem;
        conv_fused_kernel<<<dim3(SEQ / 64, HEADS, 3), 256, 0, stream>>>(
            qg, kg, vg, Qb, Kb, Vb);
        fa_fwd2_kernel<<<dim3(512), 256, 0, stream>>>(Qb, Kb, Vb, outg, lseg);
        fa_colsum2_kernel<<<dim3(512), 256, 0, stream>>>(Qb, Kb, lseg, rsg);
    } else {
        float* lseg = (float*)d_ws;
        dim3 grid(SEQ / QT, HEADS);
        fa_fwd_v1_kernel<<<grid, 256, 0, stream>>>(qg, kg, vg, outg, lseg);
        fa_colsum_v1_kernel<<<grid, 256, 0, stream>>>(qg, kg, lseg, rsg);
    }
}

// Round 11
// 95.891 us; speedup vs baseline: 1.2303x; 1.0427x over previous
//
#include <hip/hip_runtime.h>
#include <hip/hip_bf16.h>

#define HEADS 16
#define SEQ   4096
#define DIM   64
#define QT    64
#define KT    64
#define SCALE 0.125f
// SCALE * log2(e): folded into Q at conversion so scores are in log2 domain
#define CF    0.18033688011112042f
#define LOG2E 1.4426950408889634f

typedef __bf16 v8bf  __attribute__((ext_vector_type(8)));
typedef __bf16 v4bf  __attribute__((ext_vector_type(4)));
typedef float  f32x4 __attribute__((ext_vector_type(4)));

__device__ __forceinline__ __bf16 to_bf(float f) { return (__bf16)f; }
// v_exp_f32 computes 2^x; v_log_f32 computes log2(x)
__device__ __forceinline__ float ex2(float x) { return __builtin_amdgcn_exp2f(x); }
__device__ __forceinline__ float lg2(float x) { return __builtin_amdgcn_logf(x); }

__device__ __forceinline__ void gload16(const __bf16* g, __bf16* l) {
    __builtin_amdgcn_global_load_lds(
        (const __attribute__((address_space(1))) void*)g,
        (__attribute__((address_space(3))) void*)l,
        16, 0, 0);
}

// ===========================================================================
// Fused pre-pass (one launch): z=0 K [h][d][s] -> Kb [h][t][d];
// z=1 V [h][s][d] -> Vb [h][d][perm(t)]; z=2 Q scale-convert (CF folded).
// ===========================================================================
__global__ __launch_bounds__(256) void conv_fused_kernel(
    const float* __restrict__ qg, const float* __restrict__ kg,
    const float* __restrict__ vg, __bf16* __restrict__ Qb,
    __bf16* __restrict__ Kb, __bf16* __restrict__ Vb)
{
    __shared__ __bf16 ldsT[64][65];
    const int h   = blockIdx.y;
    const int t0  = blockIdx.x * 64;
    const int tid = threadIdx.x;
    const int rr  = tid >> 2;          // 0..63
    const int cq  = (tid & 3) * 16;    // 0,16,32,48

    if (blockIdx.z == 2) {
        const float* src = qg + ((size_t)h * SEQ + t0 + rr) * DIM + cq;
        __bf16* dst = Qb + ((size_t)h * SEQ + t0 + rr) * DIM + cq;
        v8bf o0, o1;
        #pragma unroll
        for (int j = 0; j < 2; ++j) {
            float4 f0 = *(const float4*)(src + 8 * j);
            float4 f1 = *(const float4*)(src + 8 * j + 4);
            v8bf o;
            o[0] = to_bf(f0.x * CF); o[1] = to_bf(f0.y * CF);
            o[2] = to_bf(f0.z * CF); o[3] = to_bf(f0.w * CF);
            o[4] = to_bf(f1.x * CF); o[5] = to_bf(f1.y * CF);
            o[6] = to_bf(f1.z * CF); o[7] = to_bf(f1.w * CF);
            if (j == 0) o0 = o; else o1 = o;
        }
        *(v8bf*)dst = o0;
        *(v8bf*)(dst + 8) = o1;
        return;
    }

    if (blockIdx.z == 0) {
        const float* src = kg + ((size_t)h * DIM + rr) * SEQ + t0 + cq;  // d=rr
        #pragma unroll
        for (int j = 0; j < 4; ++j) {
            float4 f = *(const float4*)(src + 4 * j);
            ldsT[rr][cq + 4 * j + 0] = to_bf(f.x);
            ldsT[rr][cq + 4 * j + 1] = to_bf(f.y);
            ldsT[rr][cq + 4 * j + 2] = to_bf(f.z);
            ldsT[rr][cq + 4 * j + 3] = to_bf(f.w);
        }
        __syncthreads();
        __bf16* dst = Kb + (size_t)h * SEQ * DIM + (size_t)(t0 + rr) * DIM + cq;
        v8bf o0, o1;
        #pragma unroll
        for (int i = 0; i < 8; ++i) {
            o0[i] = ldsT[cq + i][rr];
            o1[i] = ldsT[cq + 8 + i][rr];
        }
        *(v8bf*)dst = o0;
        *(v8bf*)(dst + 8) = o1;
    } else {
        const float* src = vg + ((size_t)h * SEQ + t0 + rr) * DIM + cq;  // t=rr
        #pragma unroll
        for (int j = 0; j < 4; ++j) {
            float4 f = *(const float4*)(src + 4 * j);
            ldsT[rr][cq + 4 * j + 0] = to_bf(f.x);
            ldsT[rr][cq + 4 * j + 1] = to_bf(f.y);
            ldsT[rr][cq + 4 * j + 2] = to_bf(f.z);
            ldsT[rr][cq + 4 * j + 3] = to_bf(f.w);
        }
        __syncthreads();
        __bf16* dst0 = Vb + ((size_t)h * DIM + rr) * SEQ + t0;
        const int n  = cq >> 4;
        const int c0 = 32 * (n >> 1) + 4 * (n & 1);
        #pragma unroll
        for (int j2 = 0; j2 < 4; ++j2) {
            v4bf ch;
            #pragma unroll
            for (int r = 0; r < 4; ++r)
                ch[r] = ldsT[cq + 4 * j2 + r][rr];
            *(v4bf*)(dst0 + c0 + 8 * j2) = ch;
        }
    }
}

// ===========================================================================
// Pass A v10: 8-wave blocks with intra-block key-split. Block = (h, pair a).
// Waves grp=0 take even 64-key subtiles, grp=1 odd; each wave computes BOTH
// Q-groups (qtile a and 63-a) on its subtile, sharing every ds_read across
// two MFMAs. Per-wave work = 32.5 subtile-visits for every block -> perfect
// balance at 4 waves/SIMD (2 blocks/CU x 8 waves). Partials combined across
// the grp pair through LDS scratch before the epilogue.
// ===========================================================================
__global__ __launch_bounds__(512, 4) void fa_fwd8_kernel(
    const __bf16* __restrict__ Qb, const __bf16* __restrict__ Kb,
    const __bf16* __restrict__ Vb, float* __restrict__ outg,
    float* __restrict__ lseg)
{
    const int b    = blockIdx.x;
    const int xcd  = b & 7;
    const int j    = b >> 3;           // 0..63
    const int h    = 2 * xcd + (j & 1);
    const int a    = j >> 1;           // 0..31: qtile pair (a, 63-a)
    const int tid  = threadIdx.x;      // 0..511
    const int wave = tid >> 6;         // 0..7
    const int lane = tid & 63;
    const int g    = lane >> 4;
    const int l16  = lane & 15;
    const int grp  = wave >> 2;        // 0: even subtiles; 1: odd subtiles
    const int w4   = wave & 3;
    const int wit  = w4 * 16 + l16;    // q-row within a qtile

    const int qlo = a;                 // lo qtile index
    const int qhi = 63 - a;            // hi qtile index
    const int NT  = 64 - a;            // tiles the hi group needs
    const int nIt = (NT + 1) >> 1;     // 128-key iterations

    // 64 KB pool: K tile (buf,u) at (buf*2+u)*4096; V at +16384.
    // After the loop the pool is reused as float scratch for the combine.
    __shared__ alignas(16) __bf16 ldsPool[32768];

    const int r0 = tid >> 3;           // 0..63 (512 threads cover a full tile)
    const int c0 = tid & 7;
    const size_t kOff = (size_t)r0 * DIM + (size_t)((c0 ^ (r0 & 7)) << 3);
    const size_t vOff = (size_t)r0 * SEQ + (size_t)((c0 ^ (r0 & 7)) << 3);
    const __bf16* KbH = Kb + (size_t)h * SEQ * DIM;
    const __bf16* VbH = Vb + (size_t)h * DIM * SEQ;
    const int ldsW = wave * 512;       // element base within an 8KB tile

    const int qLoRow = qlo * QT + wit;
    const int qHiRow = qhi * QT + wit;
    const __bf16* qlr = Qb + ((size_t)h * SEQ + qLoRow) * DIM + g * 8;
    const __bf16* qhr = Qb + ((size_t)h * SEQ + qHiRow) * DIM + g * 8;
    v8bf aqlo0 = *(const v8bf*)qlr;
    v8bf aqlo1 = *(const v8bf*)(qlr + 32);
    v8bf aqhi0 = *(const v8bf*)qhr;
    v8bf aqhi1 = *(const v8bf*)(qhr + 32);

    f32x4 accl[4], acch[4];
    #pragma unroll
    for (int n = 0; n < 4; ++n) {
        accl[n] = (f32x4){0.f, 0.f, 0.f, 0.f};
        acch[n] = (f32x4){0.f, 0.f, 0.f, 0.f};
    }
    float lpl[4] = {0.f, 0.f, 0.f, 0.f};
    float lph[4] = {0.f, 0.f, 0.f, 0.f};

    int cur = 0;
    // prologue: stage tiles 0,1 (NT >= 33, always in range)
    #pragma unroll
    for (int u = 0; u < 2; ++u) {
        gload16(KbH + (size_t)(64 * u) * DIM + kOff,
                ldsPool + (size_t)u * 4096 + ldsW);
        gload16(VbH + 64 * u + vOff,
                ldsPool + 16384 + (size_t)u * 4096 + ldsW);
    }
    __syncthreads();

    #pragma unroll 1
    for (int it = 0; it < nIt; ++it) {
        if (it + 1 < nIt) {            // stage next 128-key pair
            const int nbuf = cur ^ 1;
            #pragma unroll
            for (int u = 0; u < 2; ++u) {
                gload16(KbH + (size_t)(128 * (it + 1) + 64 * u) * DIM + kOff,
                        ldsPool + (size_t)(nbuf * 2 + u) * 4096 + ldsW);
                gload16(VbH + (128 * (it + 1) + 64 * u) + vOff,
                        ldsPool + 16384 + (size_t)(nbuf * 2 + u) * 4096 + ldsW);
            }
        }
        const int t = 2 * it + grp;    // this wave's subtile
        if (t <= qhi) {
            const __bf16* Kt = ldsPool + (size_t)(cur * 2 + grp) * 4096;
            const __bf16* Vt = ldsPool + 16384 + (size_t)(cur * 2 + grp) * 4096;
            if (t <= qlo) {
                // ---- both Q-groups share ak/av
                f32x4 sl[4], sh[4];
                #pragma unroll
                for (int n = 0; n < 4; ++n) {
                    sl[n] = (f32x4){0.f, 0.f, 0.f, 0.f};
                    sh[n] = (f32x4){0.f, 0.f, 0.f, 0.f};
                }
                __builtin_amdgcn_s_setprio(1);
                #pragma unroll
                for (int kk = 0; kk < 2; ++kk) {
                    #pragma unroll
                    for (int n = 0; n < 4; ++n) {
                        int row  = 16 * n + l16;
                        int byte = row * 128 + kk * 64 + g * 16;
                        byte ^= (row & 7) << 4;
                        v8bf ak = *(const v8bf*)&Kt[byte >> 1];
                        sl[n] = __builtin_amdgcn_mfma_f32_16x16x32_bf16(
                            ak, kk ? aqlo1 : aqlo0, sl[n], 0, 0, 0);
                        sh[n] = __builtin_amdgcn_mfma_f32_16x16x32_bf16(
                            ak, kk ? aqhi1 : aqhi0, sh[n], 0, 0, 0);
                    }
                }
                __builtin_amdgcn_s_setprio(0);
                if (t == qlo) {        // lo diagonal (hi diag unreachable here)
                    #pragma unroll
                    for (int n = 0; n < 4; ++n)
                        #pragma unroll
                        for (int r = 0; r < 4; ++r)
                            if (16 * n + 4 * g + r > wit) sl[n][r] = -3.0e38f;
                }
                v8bf pl0, pl1, ph0, ph1;
                #pragma unroll
                for (int n = 0; n < 4; ++n) {
                    #pragma unroll
                    for (int r = 0; r < 4; ++r) {
                        float p = ex2(sl[n][r]);
                        float q = ex2(sh[n][r]);
                        lpl[r] += p;
                        lph[r] += q;
                        if (n < 2) { pl0[(n & 1) * 4 + r] = to_bf(p);
                                     ph0[(n & 1) * 4 + r] = to_bf(q); }
                        else       { pl1[(n & 1) * 4 + r] = to_bf(p);
                                     ph1[(n & 1) * 4 + r] = to_bf(q); }
                    }
                }
                __builtin_amdgcn_s_setprio(1);
                #pragma unroll
                for (int kk = 0; kk < 2; ++kk) {
                    #pragma unroll
                    for (int n = 0; n < 4; ++n) {
                        int row  = 16 * n + l16;
                        int byte = row * 128 + kk * 64 + g * 16;
                        byte ^= (row & 7) << 4;
                        v8bf av = *(const v8bf*)&Vt[byte >> 1];
                        accl[n] = __builtin_amdgcn_mfma_f32_16x16x32_bf16(
                            av, kk ? pl1 : pl0, accl[n], 0, 0, 0);
                        acch[n] = __builtin_amdgcn_mfma_f32_16x16x32_bf16(
                            av, kk ? ph1 : ph0, acch[n], 0, 0, 0);
                    }
                }
                __builtin_amdgcn_s_setprio(0);
            } else {
                // ---- hi group only
                f32x4 sh[4];
                #pragma unroll
                for (int n = 0; n < 4; ++n) sh[n] = (f32x4){0.f, 0.f, 0.f, 0.f};
                __builtin_amdgcn_s_setprio(1);
                #pragma unroll
                for (int kk = 0; kk < 2; ++kk) {
                    #pragma unroll
                    for (int n = 0; n < 4; ++n) {
                        int row  = 16 * n + l16;
                        int byte = row * 128 + kk * 64 + g * 16;
                        byte ^= (row & 7) << 4;
                        v8bf ak = *(const v8bf*)&Kt[byte >> 1];
                        sh[n] = __builtin_amdgcn_mfma_f32_16x16x32_bf16(
                            ak, kk ? aqhi1 : aqhi0, sh[n], 0, 0, 0);
                    }
                }
                __builtin_amdgcn_s_setprio(0);
                if (t == qhi) {        // hi diagonal
                    #pragma unroll
                    for (int n = 0; n < 4; ++n)
                        #pragma unroll
                        for (int r = 0; r < 4; ++r)
                            if (16 * n + 4 * g + r > wit) sh[n][r] = -3.0e38f;
                }
                v8bf ph0, ph1;
                #pragma unroll
                for (int n = 0; n < 4; ++n) {
                    #pragma unroll
                    for (int r = 0; r < 4; ++r) {
                        float q = ex2(sh[n][r]);
                        lph[r] += q;
                        if (n < 2) ph0[(n & 1) * 4 + r] = to_bf(q);
                        else       ph1[(n & 1) * 4 + r] = to_bf(q);
                    }
                }
                __builtin_amdgcn_s_setprio(1);
                #pragma unroll
                for (int kk = 0; kk < 2; ++kk) {
                    #pragma unroll
                    for (int n = 0; n < 4; ++n) {
                        int row  = 16 * n + l16;
                        int byte = row * 128 + kk * 64 + g * 16;
                        byte ^= (row & 7) << 4;
                        v8bf av = *(const v8bf*)&Vt[byte >> 1];
                        acch[n] = __builtin_amdgcn_mfma_f32_16x16x32_bf16(
                            av, kk ? ph1 : ph0, acch[n], 0, 0, 0);
                    }
                }
                __builtin_amdgcn_s_setprio(0);
            }
        }
        __syncthreads();   // drains vmcnt: next pair staged; this buffer free
        cur ^= 1;
    }

    // ---- combine partials across the grp pair through LDS scratch.
    // grp0 writes its hi-partial to slot w4; grp1 writes its lo-partial to
    // slot 4+w4. Layout: slot*1280 + reg*64 + lane (conflict-free).
    float* scratch = (float*)ldsPool;   // 8 slots x 1280 f32 = 40 KB
    {
        float* sp = scratch + (size_t)(grp ? (4 + w4) : w4) * 1280;
        if (grp == 0) {
            #pragma unroll
            for (int n = 0; n < 4; ++n)
                #pragma unroll
                for (int r = 0; r < 4; ++r)
                    sp[(n * 4 + r) * 64 + lane] = acch[n][r];
            #pragma unroll
            for (int r = 0; r < 4; ++r) sp[(16 + r) * 64 + lane] = lph[r];
        } else {
            #pragma unroll
            for (int n = 0; n < 4; ++n)
                #pragma unroll
                for (int r = 0; r < 4; ++r)
                    sp[(n * 4 + r) * 64 + lane] = accl[n][r];
            #pragma unroll
            for (int r = 0; r < 4; ++r) sp[(16 + r) * 64 + lane] = lpl[r];
        }
    }
    __syncthreads();
    f32x4 accO[4];
    float lpO[4];
    {
        const float* op = scratch + (size_t)(grp ? w4 : (4 + w4)) * 1280;
        if (grp == 0) {
            #pragma unroll
            for (int n = 0; n < 4; ++n)
                #pragma unroll
                for (int r = 0; r < 4; ++r)
                    accO[n][r] = accl[n][r] + op[(n * 4 + r) * 64 + lane];
            #pragma unroll
            for (int r = 0; r < 4; ++r)
                lpO[r] = lpl[r] + op[(16 + r) * 64 + lane];
        } else {
            #pragma unroll
            for (int n = 0; n < 4; ++n)
                #pragma unroll
                for (int r = 0; r < 4; ++r)
                    accO[n][r] = acch[n][r] + op[(n * 4 + r) * 64 + lane];
            #pragma unroll
            for (int r = 0; r < 4; ++r)
                lpO[r] = lph[r] + op[(16 + r) * 64 + lane];
        }
    }

    // ---- epilogue: grp0 stores lo rows, grp1 stores hi rows
    const int q = (grp ? qhi : qlo) * QT + wit;
    float l = (lpO[0] + lpO[1]) + (lpO[2] + lpO[3]);
    l += __shfl_xor(l, 16);
    l += __shfl_xor(l, 32);
    const float inv = 1.0f / l;
    float* orow = outg + ((size_t)h * SEQ + q) * DIM;
    #pragma unroll
    for (int n = 0; n < 4; ++n) {
        f32x4 o = accO[n];
        o[0] *= inv; o[1] *= inv; o[2] *= inv; o[3] *= inv;
        *(f32x4*)(orow + 16 * n + 4 * g) = o;
    }
    if (g == 0)
        lseg[h * SEQ + q] = lg2(l);
}

// ===========================================================================
// Pass B (round-6 best): row_sum[t] = sum_q exp2(s_qt - lse2_q).
// Key-tile pairing (ta, 63-ta), XCD head pinning, grid 512, writes rsg.
// ===========================================================================
__global__ __launch_bounds__(256, 2) void fa_colsum2_kernel(
    const __bf16* __restrict__ Qb, const __bf16* __restrict__ Kb,
    const float* __restrict__ lseg, float* __restrict__ rsg)
{
    const int b    = blockIdx.x;
    const int xcd  = b & 7;
    const int j    = b >> 3;
    const int h    = 2 * xcd + (j & 1);
    const int ta   = j >> 1;            // 0..31
    const int tb   = 63 - ta;
    const int tid  = threadIdx.x;
    const int wave = tid >> 6;
    const int lane = tid & 63;
    const int g    = lane >> 4;
    const int l16  = lane & 15;

    __shared__ alignas(16) __bf16 ldsK2[2][KT * DIM];
    __shared__ float cs[2][4][KT];

    const int r0 = tid >> 3;
    const int c0 = tid & 7;
    const size_t kOff0 = (size_t)r0 * DIM + (size_t)((c0 ^ (r0 & 7)) << 3);
    const size_t kOff1 = (size_t)(r0 + 32) * DIM + (size_t)((c0 ^ ((r0 + 32) & 7)) << 3);
    const __bf16* KbH = Kb + (size_t)h * SEQ * DIM;
    const int ldsW = wave * 512;

    gload16(KbH + (size_t)ta * KT * DIM + kOff0, &ldsK2[0][ldsW]);
    gload16(KbH + (size_t)ta * KT * DIM + kOff1, &ldsK2[0][2048 + ldsW]);
    gload16(KbH + (size_t)tb * KT * DIM + kOff0, &ldsK2[1][ldsW]);
    gload16(KbH + (size_t)tb * KT * DIM + kOff1, &ldsK2[1][2048 + ldsW]);
    __syncthreads();

    float accA[4] = {0.f, 0.f, 0.f, 0.f};
    float accB[4] = {0.f, 0.f, 0.f, 0.f};

    #pragma unroll 1
    for (int qt = ta; qt < SEQ / QT; ++qt) {
        const int qw = qt * QT + wave * 16;
        const __bf16* qrow = Qb + ((size_t)h * SEQ + qw + l16) * DIM + g * 8;
        v8bf aq0 = *(const v8bf*)qrow;
        v8bf aq1 = *(const v8bf*)(qrow + 32);
        float4 lse4 = *(const float4*)(lseg + (size_t)h * SEQ + qw + 4 * g);

        {
            f32x4 s[4];
            #pragma unroll
            for (int n = 0; n < 4; ++n) s[n] = (f32x4){0.f, 0.f, 0.f, 0.f};
            __builtin_amdgcn_s_setprio(1);
            #pragma unroll
            for (int kk = 0; kk < 2; ++kk)
                #pragma unroll
                for (int n = 0; n < 4; ++n) {
                    int row  = 16 * n + l16;
                    int byte = row * 128 + kk * 64 + g * 16;
                    byte ^= (row & 7) << 4;
                    v8bf bk = *(const v8bf*)&ldsK2[0][byte >> 1];
                    s[n] = __builtin_amdgcn_mfma_f32_16x16x32_bf16(
                        kk ? aq1 : aq0, bk, s[n], 0, 0, 0);
                }
            __builtin_amdgcn_s_setprio(0);
            if (qt == ta) {
                #pragma unroll
                for (int n = 0; n < 4; ++n) {
                    const int key = ta * KT + 16 * n + l16;
                    #pragma unroll
                    for (int r = 0; r < 4; ++r) {
                        float e = ex2(s[n][r] - lse4[r]);
                        accA[n] += (key <= qw + 4 * g + r) ? e : 0.f;
                    }
                }
            } else {
                #pragma unroll
                for (int n = 0; n < 4; ++n)
                    #pragma unroll
                    for (int r = 0; r < 4; ++r)
                        accA[n] += ex2(s[n][r] - lse4[r]);
            }
        }
        if (qt >= tb) {
            f32x4 s[4];
            #pragma unroll
            for (int n = 0; n < 4; ++n) s[n] = (f32x4){0.f, 0.f, 0.f, 0.f};
            __builtin_amdgcn_s_setprio(1);
            #pragma unroll
            for (int kk = 0; kk < 2; ++kk)
                #pragma unroll
                for (int n = 0; n < 4; ++n) {
                    int row  = 16 * n + l16;
                    int byte = row * 128 + kk * 64 + g * 16;
                    byte ^= (row & 7) << 4;
                    v8bf bk = *(const v8bf*)&ldsK2[1][byte >> 1];
                    s[n] = __builtin_amdgcn_mfma_f32_16x16x32_bf16(
                        kk ? aq1 : aq0, bk, s[n], 0, 0, 0);
                }
            __builtin_amdgcn_s_setprio(0);
            if (qt == tb) {
                #pragma unroll
                for (int n = 0; n < 4; ++n) {
                    const int key = tb * KT + 16 * n + l16;
                    #pragma unroll
                    for (int r = 0; r < 4; ++r) {
                        float e = ex2(s[n][r] - lse4[r]);
                        accB[n] += (key <= qw + 4 * g + r) ? e : 0.f;
                    }
                }
            } else {
                #pragma unroll
                for (int n = 0; n < 4; ++n)
                    #pragma unroll
                    for (int r = 0; r < 4; ++r)
                        accB[n] += ex2(s[n][r] - lse4[r]);
            }
        }
    }

    #pragma unroll
    for (int n = 0; n < 4; ++n) {
        accA[n] += __shfl_xor(accA[n], 16);
        accA[n] += __shfl_xor(accA[n], 32);
        accB[n] += __shfl_xor(accB[n], 16);
        accB[n] += __shfl_xor(accB[n], 32);
    }
    if (lane < 16) {
        #pragma unroll
        for (int n = 0; n < 4; ++n) {
            cs[0][wave][16 * n + lane] = accA[n];
            cs[1][wave][16 * n + lane] = accB[n];
        }
    }
    __syncthreads();
    if (tid < KT) {
        rsg[(size_t)h * SEQ + ta * KT + tid] =
            cs[0][0][tid] + cs[0][1][tid] + cs[0][2][tid] + cs[0][3][tid];
    } else if (tid < 2 * KT) {
        const int t = tid - KT;
        rsg[(size_t)h * SEQ + tb * KT + t] =
            cs[1][0][t] + cs[1][1][t] + cs[1][2][t] + cs[1][3][t];
    }
}

// ===========================================================================
// Fallback (round-1, fp32 inputs, scalar staging) — used if ws too small.
// ===========================================================================
__global__ __launch_bounds__(256, 1) void fa_fwd_v1_kernel(
    const float* __restrict__ qg, const float* __restrict__ kg,
    const float* __restrict__ vg, float* __restrict__ outg,
    float* __restrict__ lseg)
{
    const int h    = blockIdx.y;
    const int q0   = blockIdx.x * QT;
    const int tid  = threadIdx.x;
    const int wave = tid >> 6;
    const int lane = tid & 63;
    const int g    = lane >> 4;
    const int l16  = lane & 15;

    __shared__ alignas(16) __bf16 ldsK[KT * DIM];
    __shared__ alignas(16) __bf16 ldsV[DIM * KT];
    __shared__ alignas(16) __bf16 ldsP[4][16 * 72];

    const int qw = q0 + wave * 16;
    v8bf aq[2];
    {
        const float* qrow = qg + ((size_t)h * SEQ + qw + l16) * DIM;
        #pragma unroll
        for (int kk = 0; kk < 2; ++kk) {
            const float* p = qrow + kk * 32 + g * 8;
            float4 f0 = *(const float4*)p;
            float4 f1 = *(const float4*)(p + 4);
            aq[kk][0] = to_bf(f0.x); aq[kk][1] = to_bf(f0.y);
            aq[kk][2] = to_bf(f0.z); aq[kk][3] = to_bf(f0.w);
            aq[kk][4] = to_bf(f1.x); aq[kk][5] = to_bf(f1.y);
            aq[kk][6] = to_bf(f1.z); aq[kk][7] = to_bf(f1.w);
        }
    }
    f32x4 acc[4];
    #pragma unroll
    for (int n = 0; n < 4; ++n) acc[n] = (f32x4){0.f, 0.f, 0.f, 0.f};
    float m_r[4], l_r[4];
    #pragma unroll
    for (int r = 0; r < 4; ++r) { m_r[r] = -__builtin_inff(); l_r[r] = 0.f; }

    const int ntiles = q0 / KT + 1;
    const int kd = tid >> 2;
    const int kc = (tid & 3) * 16;

    for (int t = 0; t < ntiles; ++t) {
        const int t0 = t * KT;
        __syncthreads();
        {
            const float* src = kg + ((size_t)h * DIM + kd) * SEQ + t0 + kc;
            #pragma unroll
            for (int j = 0; j < 4; ++j) {
                float4 f = *(const float4*)(src + 4 * j);
                #pragma unroll
                for (int i = 0; i < 4; ++i) {
                    int row  = kc + 4 * j + i;
                    int byte = row * 128 + kd * 2;
                    byte ^= (row & 7) << 4;
                    ldsK[byte >> 1] = to_bf(((const float*)&f)[i]);
                }
            }
        }
        {
            const float* src = vg + ((size_t)h * SEQ + t0 + kd) * DIM + kc;
            #pragma unroll
            for (int j = 0; j < 4; ++j) {
                float4 f = *(const float4*)(src + 4 * j);
                #pragma unroll
                for (int i = 0; i < 4; ++i) {
                    int row  = kc + 4 * j + i;
                    int byte = row * 128 + kd * 2;
                    byte ^= (row & 7) << 4;
                    ldsV[byte >> 1] = to_bf(((const float*)&f)[i]);
                }
            }
        }
        __syncthreads();

        f32x4 s[4];
        #pragma unroll
        for (int n = 0; n < 4; ++n) s[n] = (f32x4){0.f, 0.f, 0.f, 0.f};
        #pragma unroll
        for (int kk = 0; kk < 2; ++kk)
            #pragma unroll
            for (int n = 0; n < 4; ++n) {
                int row  = 16 * n + l16;
                int byte = row * 128 + kk * 64 + g * 16;
                byte ^= (row & 7) << 4;
                v8bf bk = *(const v8bf*)&ldsK[byte >> 1];
                s[n] = __builtin_amdgcn_mfma_f32_16x16x32_bf16(aq[kk], bk, s[n], 0, 0, 0);
            }
        float pvv[4][4];
        #pragma unroll
        for (int r = 0; r < 4; ++r) {
            const int qq = qw + 4 * g + r;
            float sv[4];
            #pragma unroll
            for (int n = 0; n < 4; ++n) {
                int key = t0 + 16 * n + l16;
                sv[n] = (key <= qq) ? s[n][r] * (SCALE * LOG2E) : -3.0e38f;
            }
            float mx = fmaxf(fmaxf(sv[0], sv[1]), fmaxf(sv[2], sv[3]));
            mx = fmaxf(mx, __shfl_xor(mx, 1));
            mx = fmaxf(mx, __shfl_xor(mx, 2));
            mx = fmaxf(mx, __shfl_xor(mx, 4));
            mx = fmaxf(mx, __shfl_xor(mx, 8));
            float mnew = fmaxf(m_r[r], mx);
            float corr = ex2(m_r[r] - mnew);
            m_r[r] = mnew;
            float rs = 0.f;
            #pragma unroll
            for (int n = 0; n < 4; ++n) {
                float p = (sv[n] > -1.0e38f) ? ex2(sv[n] - mnew) : 0.f;
                pvv[n][r] = p;
                rs += p;
            }
            rs += __shfl_xor(rs, 1);
            rs += __shfl_xor(rs, 2);
            rs += __shfl_xor(rs, 4);
            rs += __shfl_xor(rs, 8);
            l_r[r] = l_r[r] * corr + rs;
            #pragma unroll
            for (int n = 0; n < 4; ++n) acc[n][r] *= corr;
        }
        #pragma unroll
        for (int n = 0; n < 4; ++n)
            #pragma unroll
            for (int r = 0; r < 4; ++r)
                ldsP[wave][(4 * g + r) * 72 + 16 * n + l16] = to_bf(pvv[n][r]);
        asm volatile("s_waitcnt lgkmcnt(0)" ::: "memory");
        __builtin_amdgcn_sched_barrier(0);
        #pragma unroll
        for (int kk = 0; kk < 2; ++kk) {
            v8bf ap = *(const v8bf*)&ldsP[wave][l16 * 72 + 32 * kk + 8 * g];
            #pragma unroll
            for (int n = 0; n < 4; ++n) {
                int row  = 16 * n + l16;
                int byte = row * 128 + kk * 64 + g * 16;
                byte ^= (row & 7) << 4;
                v8bf bv = *(const v8bf*)&ldsV[byte >> 1];
                acc[n] = __builtin_amdgcn_mfma_f32_16x16x32_bf16(ap, bv, acc[n], 0, 0, 0);
            }
        }
    }
    #pragma unroll
    for (int r = 0; r < 4; ++r) {
        const int qq  = qw + 4 * g + r;
        const float inv = 1.0f / l_r[r];
        float* orow = outg + ((size_t)h * SEQ + qq) * DIM;
        #pragma unroll
        for (int n = 0; n < 4; ++n)
            orow[16 * n + l16] = acc[n][r] * inv;
        if (l16 == 0)
            lseg[h * SEQ + qq] = m_r[r] + lg2(l_r[r]);
    }
}

__global__ __launch_bounds__(256, 1) void fa_colsum_v1_kernel(
    const float* __restrict__ qg, const float* __restrict__ kg,
    const float* __restrict__ lseg, float* __restrict__ rsg)
{
    const int h    = blockIdx.y;
    const int t0   = blockIdx.x * KT;
    const int tid  = threadIdx.x;
    const int wave = tid >> 6;
    const int lane = tid & 63;
    const int g    = lane >> 4;
    const int l16  = lane & 15;

    __shared__ alignas(16) __bf16 ldsK[KT * DIM];
    __shared__ float cs[4][KT];
    {
        const int kd = tid >> 2;
        const int kc = (tid & 3) * 16;
        const float* src = kg + ((size_t)h * DIM + kd) * SEQ + t0 + kc;
        #pragma unroll
        for (int j = 0; j < 4; ++j) {
            float4 f = *(const float4*)(src + 4 * j);
            #pragma unroll
            for (int i = 0; i < 4; ++i) {
                int row  = kc + 4 * j + i;
                int byte = row * 128 + kd * 2;
                byte ^= (row & 7) << 4;
                ldsK[byte >> 1] = to_bf(((const float*)&f)[i]);
            }
        }
    }
    __syncthreads();
    float colacc[4] = {0.f, 0.f, 0.f, 0.f};
    for (int qt = t0 / QT; qt < SEQ / QT; ++qt) {
        const int qw = qt * QT + wave * 16;
        const float* qrow = qg + ((size_t)h * SEQ + qw + l16) * DIM;
        v8bf aq[2];
        #pragma unroll
        for (int kk = 0; kk < 2; ++kk) {
            const float* p = qrow + kk * 32 + g * 8;
            float4 f0 = *(const float4*)p;
            float4 f1 = *(const float4*)(p + 4);
            aq[kk][0] = to_bf(f0.x); aq[kk][1] = to_bf(f0.y);
            aq[kk][2] = to_bf(f0.z); aq[kk][3] = to_bf(f0.w);
            aq[kk][4] = to_bf(f1.x); aq[kk][5] = to_bf(f1.y);
            aq[kk][6] = to_bf(f1.z); aq[kk][7] = to_bf(f1.w);
        }
        float lse_r[4];
        #pragma unroll
        for (int r = 0; r < 4; ++r)
            lse_r[r] = lseg[h * SEQ + qw + 4 * g + r];
        f32x4 s[4];
        #pragma unroll
        for (int n = 0; n < 4; ++n) s[n] = (f32x4){0.f, 0.f, 0.f, 0.f};
        #pragma unroll
        for (int kk = 0; kk < 2; ++kk)
            #pragma unroll
            for (int n = 0; n < 4; ++n) {
                int row  = 16 * n + l16;
                int byte = row * 128 + kk * 64 + g * 16;
                byte ^= (row & 7) << 4;
                v8bf bk = *(const v8bf*)&ldsK[byte >> 1];
                s[n] = __builtin_amdgcn_mfma_f32_16x16x32_bf16(aq[kk], bk, s[n], 0, 0, 0);
            }
        #pragma unroll
        for (int n = 0; n < 4; ++n) {
            const int key = t0 + 16 * n + l16;
            #pragma unroll
            for (int r = 0; r < 4; ++r) {
                const int qq = qw + 4 * g + r;
                if (key <= qq)
                    colacc[n] += ex2(s[n][r] * (SCALE * LOG2E) - lse_r[r]);
            }
        }
    }
    #pragma unroll
    for (int n = 0; n < 4; ++n) {
        colacc[n] += __shfl_xor(colacc[n], 16);
        colacc[n] += __shfl_xor(colacc[n], 32);
    }
    if (lane < 16) {
        #pragma unroll
        for (int n = 0; n < 4; ++n)
            cs[wave][16 * n + lane] = colacc[n];
    }
    __syncthreads();
    if (tid < KT) {
        float v = cs[0][tid] + cs[1][tid] + cs[2][tid] + cs[3][tid];
        rsg[h * SEQ + t0 + tid] = v;
    }
}

extern "C" void kernel_launch(void* const* d_in, const int* in_sizes, int n_in,
                              void* d_out, int out_size, void* d_ws, size_t ws_size,
                              hipStream_t stream) {
    (void)in_sizes; (void)n_in; (void)out_size;
    const float* qg = (const float*)d_in[0];
    const float* kg = (const float*)d_in[1];
    const float* vg = (const float*)d_in[2];
    float* outg = (float*)d_out;
    float* rsg  = outg + (size_t)HEADS * SEQ * DIM;

    const size_t nElem   = (size_t)HEADS * SEQ * DIM;        // 4.19M
    const size_t lseB    = (size_t)HEADS * SEQ * sizeof(float);
    const size_t needB   = lseB + 3 * nElem * sizeof(__bf16);

    if (ws_size >= needB) {
        float*  lseg = (float*)d_ws;
        __bf16* Qb = (__bf16*)((char*)d_ws + lseB);
        __bf16* Kb = Qb + nElem;
        __bf16* Vb = Kb + nElem;
        conv_fused_kernel<<<dim3(SEQ / 64, HEADS, 3), 256, 0, stream>>>(
            qg, kg, vg, Qb, Kb, Vb);
        fa_fwd8_kernel<<<dim3(512), 512, 0, stream>>>(Qb, Kb, Vb, outg, lseg);
        fa_colsum2_kernel<<<dim3(512), 256, 0, stream>>>(Qb, Kb, lseg, rsg);
    } else {
        float* lseg = (float*)d_ws;
        dim3 grid(SEQ / QT, HEADS);
        fa_fwd_v1_kernel<<<grid, 256, 0, stream>>>(qg, kg, vg, outg, lseg);
        fa_colsum_v1_kernel<<<grid, 256, 0, stream>>>(qg, kg, lseg, rsg);
    }
}

// Round 12
// 94.537 us; speedup vs baseline: 1.2479x; 1.0143x over previous
//
#include <hip/hip_runtime.h>
#include <hip/hip_bf16.h>

#define HEADS 16
#define SEQ   4096
#define DIM   64
#define QT    64
#define KT    64
#define SCALE 0.125f
// SCALE * log2(e): folded into Q at conversion so scores are in log2 domain
#define CF    0.18033688011112042f
#define LOG2E 1.4426950408889634f

typedef __bf16 v8bf  __attribute__((ext_vector_type(8)));
typedef __bf16 v4bf  __attribute__((ext_vector_type(4)));
typedef float  f32x4 __attribute__((ext_vector_type(4)));

__device__ __forceinline__ __bf16 to_bf(float f) { return (__bf16)f; }
// v_exp_f32 computes 2^x; v_log_f32 computes log2(x)
__device__ __forceinline__ float ex2(float x) { return __builtin_amdgcn_exp2f(x); }
__device__ __forceinline__ float lg2(float x) { return __builtin_amdgcn_logf(x); }

__device__ __forceinline__ void gload16(const __bf16* g, __bf16* l) {
    __builtin_amdgcn_global_load_lds(
        (const __attribute__((address_space(1))) void*)g,
        (__attribute__((address_space(3))) void*)l,
        16, 0, 0);
}

// ===========================================================================
// Fused pre-pass (one launch): z=0 K [h][d][s] -> Kb [h][t][d];
// z=1 V [h][s][d] -> Vb [h][d][perm(t)]; z=2 Q scale-convert (CF folded).
// ===========================================================================
__global__ __launch_bounds__(256) void conv_fused_kernel(
    const float* __restrict__ qg, const float* __restrict__ kg,
    const float* __restrict__ vg, __bf16* __restrict__ Qb,
    __bf16* __restrict__ Kb, __bf16* __restrict__ Vb)
{
    __shared__ __bf16 ldsT[64][65];
    const int h   = blockIdx.y;
    const int t0  = blockIdx.x * 64;
    const int tid = threadIdx.x;
    const int rr  = tid >> 2;          // 0..63
    const int cq  = (tid & 3) * 16;    // 0,16,32,48

    if (blockIdx.z == 2) {
        const float* src = qg + ((size_t)h * SEQ + t0 + rr) * DIM + cq;
        __bf16* dst = Qb + ((size_t)h * SEQ + t0 + rr) * DIM + cq;
        v8bf o0, o1;
        #pragma unroll
        for (int j = 0; j < 2; ++j) {
            float4 f0 = *(const float4*)(src + 8 * j);
            float4 f1 = *(const float4*)(src + 8 * j + 4);
            v8bf o;
            o[0] = to_bf(f0.x * CF); o[1] = to_bf(f0.y * CF);
            o[2] = to_bf(f0.z * CF); o[3] = to_bf(f0.w * CF);
            o[4] = to_bf(f1.x * CF); o[5] = to_bf(f1.y * CF);
            o[6] = to_bf(f1.z * CF); o[7] = to_bf(f1.w * CF);
            if (j == 0) o0 = o; else o1 = o;
        }
        *(v8bf*)dst = o0;
        *(v8bf*)(dst + 8) = o1;
        return;
    }

    if (blockIdx.z == 0) {
        const float* src = kg + ((size_t)h * DIM + rr) * SEQ + t0 + cq;  // d=rr
        #pragma unroll
        for (int j = 0; j < 4; ++j) {
            float4 f = *(const float4*)(src + 4 * j);
            ldsT[rr][cq + 4 * j + 0] = to_bf(f.x);
            ldsT[rr][cq + 4 * j + 1] = to_bf(f.y);
            ldsT[rr][cq + 4 * j + 2] = to_bf(f.z);
            ldsT[rr][cq + 4 * j + 3] = to_bf(f.w);
        }
        __syncthreads();
        __bf16* dst = Kb + (size_t)h * SEQ * DIM + (size_t)(t0 + rr) * DIM + cq;
        v8bf o0, o1;
        #pragma unroll
        for (int i = 0; i < 8; ++i) {
            o0[i] = ldsT[cq + i][rr];
            o1[i] = ldsT[cq + 8 + i][rr];
        }
        *(v8bf*)dst = o0;
        *(v8bf*)(dst + 8) = o1;
    } else {
        const float* src = vg + ((size_t)h * SEQ + t0 + rr) * DIM + cq;  // t=rr
        #pragma unroll
        for (int j = 0; j < 4; ++j) {
            float4 f = *(const float4*)(src + 4 * j);
            ldsT[rr][cq + 4 * j + 0] = to_bf(f.x);
            ldsT[rr][cq + 4 * j + 1] = to_bf(f.y);
            ldsT[rr][cq + 4 * j + 2] = to_bf(f.z);
            ldsT[rr][cq + 4 * j + 3] = to_bf(f.w);
        }
        __syncthreads();
        __bf16* dst0 = Vb + ((size_t)h * DIM + rr) * SEQ + t0;
        const int n  = cq >> 4;
        const int c0 = 32 * (n >> 1) + 4 * (n & 1);
        #pragma unroll
        for (int j2 = 0; j2 < 4; ++j2) {
            v4bf ch;
            #pragma unroll
            for (int r = 0; r < 4; ++r)
                ch[r] = ldsT[cq + 4 * j2 + r][rr];
            *(v4bf*)(dst0 + c0 + 8 * j2) = ch;
        }
    }
}

// ===========================================================================
// Pass A v10 (round-11, 53.2us measured): 8-wave blocks, intra-block
// key-split, both Q-groups share each ds_read, LDS-scratch combine.
// ===========================================================================
__global__ __launch_bounds__(512, 4) void fa_fwd8_kernel(
    const __bf16* __restrict__ Qb, const __bf16* __restrict__ Kb,
    const __bf16* __restrict__ Vb, float* __restrict__ outg,
    float* __restrict__ lseg)
{
    const int b    = blockIdx.x;
    const int xcd  = b & 7;
    const int j    = b >> 3;           // 0..63
    const int h    = 2 * xcd + (j & 1);
    const int a    = j >> 1;           // 0..31: qtile pair (a, 63-a)
    const int tid  = threadIdx.x;      // 0..511
    const int wave = tid >> 6;         // 0..7
    const int lane = tid & 63;
    const int g    = lane >> 4;
    const int l16  = lane & 15;
    const int grp  = wave >> 2;        // 0: even subtiles; 1: odd subtiles
    const int w4   = wave & 3;
    const int wit  = w4 * 16 + l16;    // q-row within a qtile

    const int qlo = a;
    const int qhi = 63 - a;
    const int NT  = 64 - a;
    const int nIt = (NT + 1) >> 1;

    __shared__ alignas(16) __bf16 ldsPool[32768];

    const int r0 = tid >> 3;           // 0..63
    const int c0 = tid & 7;
    const size_t kOff = (size_t)r0 * DIM + (size_t)((c0 ^ (r0 & 7)) << 3);
    const size_t vOff = (size_t)r0 * SEQ + (size_t)((c0 ^ (r0 & 7)) << 3);
    const __bf16* KbH = Kb + (size_t)h * SEQ * DIM;
    const __bf16* VbH = Vb + (size_t)h * DIM * SEQ;
    const int ldsW = wave * 512;

    const int qLoRow = qlo * QT + wit;
    const int qHiRow = qhi * QT + wit;
    const __bf16* qlr = Qb + ((size_t)h * SEQ + qLoRow) * DIM + g * 8;
    const __bf16* qhr = Qb + ((size_t)h * SEQ + qHiRow) * DIM + g * 8;
    v8bf aqlo0 = *(const v8bf*)qlr;
    v8bf aqlo1 = *(const v8bf*)(qlr + 32);
    v8bf aqhi0 = *(const v8bf*)qhr;
    v8bf aqhi1 = *(const v8bf*)(qhr + 32);

    f32x4 accl[4], acch[4];
    #pragma unroll
    for (int n = 0; n < 4; ++n) {
        accl[n] = (f32x4){0.f, 0.f, 0.f, 0.f};
        acch[n] = (f32x4){0.f, 0.f, 0.f, 0.f};
    }
    float lpl[4] = {0.f, 0.f, 0.f, 0.f};
    float lph[4] = {0.f, 0.f, 0.f, 0.f};

    int cur = 0;
    #pragma unroll
    for (int u = 0; u < 2; ++u) {
        gload16(KbH + (size_t)(64 * u) * DIM + kOff,
                ldsPool + (size_t)u * 4096 + ldsW);
        gload16(VbH + 64 * u + vOff,
                ldsPool + 16384 + (size_t)u * 4096 + ldsW);
    }
    __syncthreads();

    #pragma unroll 1
    for (int it = 0; it < nIt; ++it) {
        if (it + 1 < nIt) {
            const int nbuf = cur ^ 1;
            #pragma unroll
            for (int u = 0; u < 2; ++u) {
                gload16(KbH + (size_t)(128 * (it + 1) + 64 * u) * DIM + kOff,
                        ldsPool + (size_t)(nbuf * 2 + u) * 4096 + ldsW);
                gload16(VbH + (128 * (it + 1) + 64 * u) + vOff,
                        ldsPool + 16384 + (size_t)(nbuf * 2 + u) * 4096 + ldsW);
            }
        }
        const int t = 2 * it + grp;
        if (t <= qhi) {
            const __bf16* Kt = ldsPool + (size_t)(cur * 2 + grp) * 4096;
            const __bf16* Vt = ldsPool + 16384 + (size_t)(cur * 2 + grp) * 4096;
            if (t <= qlo) {
                f32x4 sl[4], sh[4];
                #pragma unroll
                for (int n = 0; n < 4; ++n) {
                    sl[n] = (f32x4){0.f, 0.f, 0.f, 0.f};
                    sh[n] = (f32x4){0.f, 0.f, 0.f, 0.f};
                }
                __builtin_amdgcn_s_setprio(1);
                #pragma unroll
                for (int kk = 0; kk < 2; ++kk) {
                    #pragma unroll
                    for (int n = 0; n < 4; ++n) {
                        int row  = 16 * n + l16;
                        int byte = row * 128 + kk * 64 + g * 16;
                        byte ^= (row & 7) << 4;
                        v8bf ak = *(const v8bf*)&Kt[byte >> 1];
                        sl[n] = __builtin_amdgcn_mfma_f32_16x16x32_bf16(
                            ak, kk ? aqlo1 : aqlo0, sl[n], 0, 0, 0);
                        sh[n] = __builtin_amdgcn_mfma_f32_16x16x32_bf16(
                            ak, kk ? aqhi1 : aqhi0, sh[n], 0, 0, 0);
                    }
                }
                __builtin_amdgcn_s_setprio(0);
                if (t == qlo) {
                    #pragma unroll
                    for (int n = 0; n < 4; ++n)
                        #pragma unroll
                        for (int r = 0; r < 4; ++r)
                            if (16 * n + 4 * g + r > wit) sl[n][r] = -3.0e38f;
                }
                v8bf pl0, pl1, ph0, ph1;
                #pragma unroll
                for (int n = 0; n < 4; ++n) {
                    #pragma unroll
                    for (int r = 0; r < 4; ++r) {
                        float p = ex2(sl[n][r]);
                        float q = ex2(sh[n][r]);
                        lpl[r] += p;
                        lph[r] += q;
                        if (n < 2) { pl0[(n & 1) * 4 + r] = to_bf(p);
                                     ph0[(n & 1) * 4 + r] = to_bf(q); }
                        else       { pl1[(n & 1) * 4 + r] = to_bf(p);
                                     ph1[(n & 1) * 4 + r] = to_bf(q); }
                    }
                }
                __builtin_amdgcn_s_setprio(1);
                #pragma unroll
                for (int kk = 0; kk < 2; ++kk) {
                    #pragma unroll
                    for (int n = 0; n < 4; ++n) {
                        int row  = 16 * n + l16;
                        int byte = row * 128 + kk * 64 + g * 16;
                        byte ^= (row & 7) << 4;
                        v8bf av = *(const v8bf*)&Vt[byte >> 1];
                        accl[n] = __builtin_amdgcn_mfma_f32_16x16x32_bf16(
                            av, kk ? pl1 : pl0, accl[n], 0, 0, 0);
                        acch[n] = __builtin_amdgcn_mfma_f32_16x16x32_bf16(
                            av, kk ? ph1 : ph0, acch[n], 0, 0, 0);
                    }
                }
                __builtin_amdgcn_s_setprio(0);
            } else {
                f32x4 sh[4];
                #pragma unroll
                for (int n = 0; n < 4; ++n) sh[n] = (f32x4){0.f, 0.f, 0.f, 0.f};
                __builtin_amdgcn_s_setprio(1);
                #pragma unroll
                for (int kk = 0; kk < 2; ++kk) {
                    #pragma unroll
                    for (int n = 0; n < 4; ++n) {
                        int row  = 16 * n + l16;
                        int byte = row * 128 + kk * 64 + g * 16;
                        byte ^= (row & 7) << 4;
                        v8bf ak = *(const v8bf*)&Kt[byte >> 1];
                        sh[n] = __builtin_amdgcn_mfma_f32_16x16x32_bf16(
                            ak, kk ? aqhi1 : aqhi0, sh[n], 0, 0, 0);
                    }
                }
                __builtin_amdgcn_s_setprio(0);
                if (t == qhi) {
                    #pragma unroll
                    for (int n = 0; n < 4; ++n)
                        #pragma unroll
                        for (int r = 0; r < 4; ++r)
                            if (16 * n + 4 * g + r > wit) sh[n][r] = -3.0e38f;
                }
                v8bf ph0, ph1;
                #pragma unroll
                for (int n = 0; n < 4; ++n) {
                    #pragma unroll
                    for (int r = 0; r < 4; ++r) {
                        float q = ex2(sh[n][r]);
                        lph[r] += q;
                        if (n < 2) ph0[(n & 1) * 4 + r] = to_bf(q);
                        else       ph1[(n & 1) * 4 + r] = to_bf(q);
                    }
                }
                __builtin_amdgcn_s_setprio(1);
                #pragma unroll
                for (int kk = 0; kk < 2; ++kk) {
                    #pragma unroll
                    for (int n = 0; n < 4; ++n) {
                        int row  = 16 * n + l16;
                        int byte = row * 128 + kk * 64 + g * 16;
                        byte ^= (row & 7) << 4;
                        v8bf av = *(const v8bf*)&Vt[byte >> 1];
                        acch[n] = __builtin_amdgcn_mfma_f32_16x16x32_bf16(
                            av, kk ? ph1 : ph0, acch[n], 0, 0, 0);
                    }
                }
                __builtin_amdgcn_s_setprio(0);
            }
        }
        __syncthreads();
        cur ^= 1;
    }

    // ---- combine partials across the grp pair through LDS scratch
    float* scratch = (float*)ldsPool;
    {
        float* sp = scratch + (size_t)(grp ? (4 + w4) : w4) * 1280;
        if (grp == 0) {
            #pragma unroll
            for (int n = 0; n < 4; ++n)
                #pragma unroll
                for (int r = 0; r < 4; ++r)
                    sp[(n * 4 + r) * 64 + lane] = acch[n][r];
            #pragma unroll
            for (int r = 0; r < 4; ++r) sp[(16 + r) * 64 + lane] = lph[r];
        } else {
            #pragma unroll
            for (int n = 0; n < 4; ++n)
                #pragma unroll
                for (int r = 0; r < 4; ++r)
                    sp[(n * 4 + r) * 64 + lane] = accl[n][r];
            #pragma unroll
            for (int r = 0; r < 4; ++r) sp[(16 + r) * 64 + lane] = lpl[r];
        }
    }
    __syncthreads();
    f32x4 accO[4];
    float lpO[4];
    {
        const float* op = scratch + (size_t)(grp ? w4 : (4 + w4)) * 1280;
        if (grp == 0) {
            #pragma unroll
            for (int n = 0; n < 4; ++n)
                #pragma unroll
                for (int r = 0; r < 4; ++r)
                    accO[n][r] = accl[n][r] + op[(n * 4 + r) * 64 + lane];
            #pragma unroll
            for (int r = 0; r < 4; ++r)
                lpO[r] = lpl[r] + op[(16 + r) * 64 + lane];
        } else {
            #pragma unroll
            for (int n = 0; n < 4; ++n)
                #pragma unroll
                for (int r = 0; r < 4; ++r)
                    accO[n][r] = acch[n][r] + op[(n * 4 + r) * 64 + lane];
            #pragma unroll
            for (int r = 0; r < 4; ++r)
                lpO[r] = lph[r] + op[(16 + r) * 64 + lane];
        }
    }

    const int q = (grp ? qhi : qlo) * QT + wit;
    float l = (lpO[0] + lpO[1]) + (lpO[2] + lpO[3]);
    l += __shfl_xor(l, 16);
    l += __shfl_xor(l, 32);
    const float inv = 1.0f / l;
    float* orow = outg + ((size_t)h * SEQ + q) * DIM;
    #pragma unroll
    for (int n = 0; n < 4; ++n) {
        f32x4 o = accO[n];
        o[0] *= inv; o[1] *= inv; o[2] *= inv; o[3] *= inv;
        *(f32x4*)(orow + 16 * n + 4 * g) = o;
    }
    if (g == 0)
        lseg[h * SEQ + q] = lg2(l);
}

// ===========================================================================
// Pass B v4: 8-wave colsum. Same (h, ta) decode and (ta, 63-ta) pairing;
// waves grp=0 take even qt, grp=1 odd qt; w4 owns the 16-row q-slice.
// Per-wave MFMA work = 65/2 tile-visits, constant across blocks.
// 4 waves/SIMD (2 blocks/CU x 8 waves). 8-way cross-wave LDS reduce.
// ===========================================================================
__global__ __launch_bounds__(512, 4) void fa_colsum8_kernel(
    const __bf16* __restrict__ Qb, const __bf16* __restrict__ Kb,
    const float* __restrict__ lseg, float* __restrict__ rsg)
{
    const int b    = blockIdx.x;
    const int xcd  = b & 7;
    const int j    = b >> 3;
    const int h    = 2 * xcd + (j & 1);
    const int ta   = j >> 1;            // 0..31
    const int tb   = 63 - ta;
    const int tid  = threadIdx.x;       // 0..511
    const int wave = tid >> 6;          // 0..7
    const int lane = tid & 63;
    const int g    = lane >> 4;
    const int l16  = lane & 15;
    const int grp  = wave >> 2;         // qt parity
    const int w4   = wave & 3;          // q-slice within qtile

    __shared__ alignas(16) __bf16 ldsK2[2][KT * DIM];   // 16 KB
    __shared__ float cs[2][8][KT];                      // 4 KB

    // staging: 512 threads cover a full 8KB tile (one gload16 each)
    const int r0 = tid >> 3;            // 0..63
    const int c0 = tid & 7;
    const size_t kOff = (size_t)r0 * DIM + (size_t)((c0 ^ (r0 & 7)) << 3);
    const __bf16* KbH = Kb + (size_t)h * SEQ * DIM;
    const int ldsW = wave * 512;

    gload16(KbH + (size_t)ta * KT * DIM + kOff, &ldsK2[0][ldsW]);
    gload16(KbH + (size_t)tb * KT * DIM + kOff, &ldsK2[1][ldsW]);
    __syncthreads();

    float accA[4] = {0.f, 0.f, 0.f, 0.f};
    float accB[4] = {0.f, 0.f, 0.f, 0.f};

    #pragma unroll 1
    for (int qt = ta + grp; qt < SEQ / QT; qt += 2) {
        const int qw = qt * QT + w4 * 16;
        const __bf16* qrow = Qb + ((size_t)h * SEQ + qw + l16) * DIM + g * 8;
        v8bf aq0 = *(const v8bf*)qrow;
        v8bf aq1 = *(const v8bf*)(qrow + 32);
        float4 lse4 = *(const float4*)(lseg + (size_t)h * SEQ + qw + 4 * g);

        // ---- tile A (always active; qt >= ta by construction)
        {
            f32x4 s[4];
            #pragma unroll
            for (int n = 0; n < 4; ++n) s[n] = (f32x4){0.f, 0.f, 0.f, 0.f};
            __builtin_amdgcn_s_setprio(1);
            #pragma unroll
            for (int kk = 0; kk < 2; ++kk)
                #pragma unroll
                for (int n = 0; n < 4; ++n) {
                    int row  = 16 * n + l16;
                    int byte = row * 128 + kk * 64 + g * 16;
                    byte ^= (row & 7) << 4;
                    v8bf bk = *(const v8bf*)&ldsK2[0][byte >> 1];
                    s[n] = __builtin_amdgcn_mfma_f32_16x16x32_bf16(
                        kk ? aq1 : aq0, bk, s[n], 0, 0, 0);
                }
            __builtin_amdgcn_s_setprio(0);
            if (qt == ta) {
                #pragma unroll
                for (int n = 0; n < 4; ++n) {
                    const int key = ta * KT + 16 * n + l16;
                    #pragma unroll
                    for (int r = 0; r < 4; ++r) {
                        float e = ex2(s[n][r] - lse4[r]);
                        accA[n] += (key <= qw + 4 * g + r) ? e : 0.f;
                    }
                }
            } else {
                #pragma unroll
                for (int n = 0; n < 4; ++n)
                    #pragma unroll
                    for (int r = 0; r < 4; ++r)
                        accA[n] += ex2(s[n][r] - lse4[r]);
            }
        }
        // ---- tile B (active for qt >= tb)
        if (qt >= tb) {
            f32x4 s[4];
            #pragma unroll
            for (int n = 0; n < 4; ++n) s[n] = (f32x4){0.f, 0.f, 0.f, 0.f};
            __builtin_amdgcn_s_setprio(1);
            #pragma unroll
            for (int kk = 0; kk < 2; ++kk)
                #pragma unroll
                for (int n = 0; n < 4; ++n) {
                    int row  = 16 * n + l16;
                    int byte = row * 128 + kk * 64 + g * 16;
                    byte ^= (row & 7) << 4;
                    v8bf bk = *(const v8bf*)&ldsK2[1][byte >> 1];
                    s[n] = __builtin_amdgcn_mfma_f32_16x16x32_bf16(
                        kk ? aq1 : aq0, bk, s[n], 0, 0, 0);
                }
            __builtin_amdgcn_s_setprio(0);
            if (qt == tb) {
                #pragma unroll
                for (int n = 0; n < 4; ++n) {
                    const int key = tb * KT + 16 * n + l16;
                    #pragma unroll
                    for (int r = 0; r < 4; ++r) {
                        float e = ex2(s[n][r] - lse4[r]);
                        accB[n] += (key <= qw + 4 * g + r) ? e : 0.f;
                    }
                }
            } else {
                #pragma unroll
                for (int n = 0; n < 4; ++n)
                    #pragma unroll
                    for (int r = 0; r < 4; ++r)
                        accB[n] += ex2(s[n][r] - lse4[r]);
            }
        }
    }

    #pragma unroll
    for (int n = 0; n < 4; ++n) {
        accA[n] += __shfl_xor(accA[n], 16);
        accA[n] += __shfl_xor(accA[n], 32);
        accB[n] += __shfl_xor(accB[n], 16);
        accB[n] += __shfl_xor(accB[n], 32);
    }
    if (lane < 16) {
        #pragma unroll
        for (int n = 0; n < 4; ++n) {
            cs[0][wave][16 * n + lane] = accA[n];
            cs[1][wave][16 * n + lane] = accB[n];
        }
    }
    __syncthreads();
    if (tid < KT) {
        float v = 0.f;
        #pragma unroll
        for (int w = 0; w < 8; ++w) v += cs[0][w][tid];
        rsg[(size_t)h * SEQ + ta * KT + tid] = v;
    } else if (tid < 2 * KT) {
        const int t = tid - KT;
        float v = 0.f;
        #pragma unroll
        for (int w = 0; w < 8; ++w) v += cs[1][w][t];
        rsg[(size_t)h * SEQ + tb * KT + t] = v;
    }
}

// ===========================================================================
// Fallback (round-1, fp32 inputs, scalar staging) — used if ws too small.
// ===========================================================================
__global__ __launch_bounds__(256, 1) void fa_fwd_v1_kernel(
    const float* __restrict__ qg, const float* __restrict__ kg,
    const float* __restrict__ vg, float* __restrict__ outg,
    float* __restrict__ lseg)
{
    const int h    = blockIdx.y;
    const int q0   = blockIdx.x * QT;
    const int tid  = threadIdx.x;
    const int wave = tid >> 6;
    const int lane = tid & 63;
    const int g    = lane >> 4;
    const int l16  = lane & 15;

    __shared__ alignas(16) __bf16 ldsK[KT * DIM];
    __shared__ alignas(16) __bf16 ldsV[DIM * KT];
    __shared__ alignas(16) __bf16 ldsP[4][16 * 72];

    const int qw = q0 + wave * 16;
    v8bf aq[2];
    {
        const float* qrow = qg + ((size_t)h * SEQ + qw + l16) * DIM;
        #pragma unroll
        for (int kk = 0; kk < 2; ++kk) {
            const float* p = qrow + kk * 32 + g * 8;
            float4 f0 = *(const float4*)p;
            float4 f1 = *(const float4*)(p + 4);
            aq[kk][0] = to_bf(f0.x); aq[kk][1] = to_bf(f0.y);
            aq[kk][2] = to_bf(f0.z); aq[kk][3] = to_bf(f0.w);
            aq[kk][4] = to_bf(f1.x); aq[kk][5] = to_bf(f1.y);
            aq[kk][6] = to_bf(f1.z); aq[kk][7] = to_bf(f1.w);
        }
    }
    f32x4 acc[4];
    #pragma unroll
    for (int n = 0; n < 4; ++n) acc[n] = (f32x4){0.f, 0.f, 0.f, 0.f};
    float m_r[4], l_r[4];
    #pragma unroll
    for (int r = 0; r < 4; ++r) { m_r[r] = -__builtin_inff(); l_r[r] = 0.f; }

    const int ntiles = q0 / KT + 1;
    const int kd = tid >> 2;
    const int kc = (tid & 3) * 16;

    for (int t = 0; t < ntiles; ++t) {
        const int t0 = t * KT;
        __syncthreads();
        {
            const float* src = kg + ((size_t)h * DIM + kd) * SEQ + t0 + kc;
            #pragma unroll
            for (int j = 0; j < 4; ++j) {
                float4 f = *(const float4*)(src + 4 * j);
                #pragma unroll
                for (int i = 0; i < 4; ++i) {
                    int row  = kc + 4 * j + i;
                    int byte = row * 128 + kd * 2;
                    byte ^= (row & 7) << 4;
                    ldsK[byte >> 1] = to_bf(((const float*)&f)[i]);
                }
            }
        }
        {
            const float* src = vg + ((size_t)h * SEQ + t0 + kd) * DIM + kc;
            #pragma unroll
            for (int j = 0; j < 4; ++j) {
                float4 f = *(const float4*)(src + 4 * j);
                #pragma unroll
                for (int i = 0; i < 4; ++i) {
                    int row  = kc + 4 * j + i;
                    int byte = row * 128 + kd * 2;
                    byte ^= (row & 7) << 4;
                    ldsV[byte >> 1] = to_bf(((const float*)&f)[i]);
                }
            }
        }
        __syncthreads();

        f32x4 s[4];
        #pragma unroll
        for (int n = 0; n < 4; ++n) s[n] = (f32x4){0.f, 0.f, 0.f, 0.f};
        #pragma unroll
        for (int kk = 0; kk < 2; ++kk)
            #pragma unroll
            for (int n = 0; n < 4; ++n) {
                int row  = 16 * n + l16;
                int byte = row * 128 + kk * 64 + g * 16;
                byte ^= (row & 7) << 4;
                v8bf bk = *(const v8bf*)&ldsK[byte >> 1];
                s[n] = __builtin_amdgcn_mfma_f32_16x16x32_bf16(aq[kk], bk, s[n], 0, 0, 0);
            }
        float pvv[4][4];
        #pragma unroll
        for (int r = 0; r < 4; ++r) {
            const int qq = qw + 4 * g + r;
            float sv[4];
            #pragma unroll
            for (int n = 0; n < 4; ++n) {
                int key = t0 + 16 * n + l16;
                sv[n] = (key <= qq) ? s[n][r] * (SCALE * LOG2E) : -3.0e38f;
            }
            float mx = fmaxf(fmaxf(sv[0], sv[1]), fmaxf(sv[2], sv[3]));
            mx = fmaxf(mx, __shfl_xor(mx, 1));
            mx = fmaxf(mx, __shfl_xor(mx, 2));
            mx = fmaxf(mx, __shfl_xor(mx, 4));
            mx = fmaxf(mx, __shfl_xor(mx, 8));
            float mnew = fmaxf(m_r[r], mx);
            float corr = ex2(m_r[r] - mnew);
            m_r[r] = mnew;
            float rs = 0.f;
            #pragma unroll
            for (int n = 0; n < 4; ++n) {
                float p = (sv[n] > -1.0e38f) ? ex2(sv[n] - mnew) : 0.f;
                pvv[n][r] = p;
                rs += p;
            }
            rs += __shfl_xor(rs, 1);
            rs += __shfl_xor(rs, 2);
            rs += __shfl_xor(rs, 4);
            rs += __shfl_xor(rs, 8);
            l_r[r] = l_r[r] * corr + rs;
            #pragma unroll
            for (int n = 0; n < 4; ++n) acc[n][r] *= corr;
        }
        #pragma unroll
        for (int n = 0; n < 4; ++n)
            #pragma unroll
            for (int r = 0; r < 4; ++r)
                ldsP[wave][(4 * g + r) * 72 + 16 * n + l16] = to_bf(pvv[n][r]);
        asm volatile("s_waitcnt lgkmcnt(0)" ::: "memory");
        __builtin_amdgcn_sched_barrier(0);
        #pragma unroll
        for (int kk = 0; kk < 2; ++kk) {
            v8bf ap = *(const v8bf*)&ldsP[wave][l16 * 72 + 32 * kk + 8 * g];
            #pragma unroll
            for (int n = 0; n < 4; ++n) {
                int row  = 16 * n + l16;
                int byte = row * 128 + kk * 64 + g * 16;
                byte ^= (row & 7) << 4;
                v8bf bv = *(const v8bf*)&ldsV[byte >> 1];
                acc[n] = __builtin_amdgcn_mfma_f32_16x16x32_bf16(ap, bv, acc[n], 0, 0, 0);
            }
        }
    }
    #pragma unroll
    for (int r = 0; r < 4; ++r) {
        const int qq  = qw + 4 * g + r;
        const float inv = 1.0f / l_r[r];
        float* orow = outg + ((size_t)h * SEQ + qq) * DIM;
        #pragma unroll
        for (int n = 0; n < 4; ++n)
            orow[16 * n + l16] = acc[n][r] * inv;
        if (l16 == 0)
            lseg[h * SEQ + qq] = m_r[r] + lg2(l_r[r]);
    }
}

__global__ __launch_bounds__(256, 1) void fa_colsum_v1_kernel(
    const float* __restrict__ qg, const float* __restrict__ kg,
    const float* __restrict__ lseg, float* __restrict__ rsg)
{
    const int h    = blockIdx.y;
    const int t0   = blockIdx.x * KT;
    const int tid  = threadIdx.x;
    const int wave = tid >> 6;
    const int lane = tid & 63;
    const int g    = lane >> 4;
    const int l16  = lane & 15;

    __shared__ alignas(16) __bf16 ldsK[KT * DIM];
    __shared__ float cs[4][KT];
    {
        const int kd = tid >> 2;
        const int kc = (tid & 3) * 16;
        const float* src = kg + ((size_t)h * DIM + kd) * SEQ + t0 + kc;
        #pragma unroll
        for (int j = 0; j < 4; ++j) {
            float4 f = *(const float4*)(src + 4 * j);
            #pragma unroll
            for (int i = 0; i < 4; ++i) {
                int row  = kc + 4 * j + i;
                int byte = row * 128 + kd * 2;
                byte ^= (row & 7) << 4;
                ldsK[byte >> 1] = to_bf(((const float*)&f)[i]);
            }
        }
    }
    __syncthreads();
    float colacc[4] = {0.f, 0.f, 0.f, 0.f};
    for (int qt = t0 / QT; qt < SEQ / QT; ++qt) {
        const int qw = qt * QT + wave * 16;
        const float* qrow = qg + ((size_t)h * SEQ + qw + l16) * DIM;
        v8bf aq[2];
        #pragma unroll
        for (int kk = 0; kk < 2; ++kk) {
            const float* p = qrow + kk * 32 + g * 8;
            float4 f0 = *(const float4*)p;
            float4 f1 = *(const float4*)(p + 4);
            aq[kk][0] = to_bf(f0.x); aq[kk][1] = to_bf(f0.y);
            aq[kk][2] = to_bf(f0.z); aq[kk][3] = to_bf(f0.w);
            aq[kk][4] = to_bf(f1.x); aq[kk][5] = to_bf(f1.y);
            aq[kk][6] = to_bf(f1.z); aq[kk][7] = to_bf(f1.w);
        }
        float lse_r[4];
        #pragma unroll
        for (int r = 0; r < 4; ++r)
            lse_r[r] = lseg[h * SEQ + qw + 4 * g + r];
        f32x4 s[4];
        #pragma unroll
        for (int n = 0; n < 4; ++n) s[n] = (f32x4){0.f, 0.f, 0.f, 0.f};
        #pragma unroll
        for (int kk = 0; kk < 2; ++kk)
            #pragma unroll
            for (int n = 0; n < 4; ++n) {
                int row  = 16 * n + l16;
                int byte = row * 128 + kk * 64 + g * 16;
                byte ^= (row & 7) << 4;
                v8bf bk = *(const v8bf*)&ldsK[byte >> 1];
                s[n] = __builtin_amdgcn_mfma_f32_16x16x32_bf16(aq[kk], bk, s[n], 0, 0, 0);
            }
        #pragma unroll
        for (int n = 0; n < 4; ++n) {
            const int key = t0 + 16 * n + l16;
            #pragma unroll
            for (int r = 0; r < 4; ++r) {
                const int qq = qw + 4 * g + r;
                if (key <= qq)
                    colacc[n] += ex2(s[n][r] * (SCALE * LOG2E) - lse_r[r]);
            }
        }
    }
    #pragma unroll
    for (int n = 0; n < 4; ++n) {
        colacc[n] += __shfl_xor(colacc[n], 16);
        colacc[n] += __shfl_xor(colacc[n], 32);
    }
    if (lane < 16) {
        #pragma unroll
        for (int n = 0; n < 4; ++n)
            cs[wave][16 * n + lane] = colacc[n];
    }
    __syncthreads();
    if (tid < KT) {
        float v = cs[0][tid] + cs[1][tid] + cs[2][tid] + cs[3][tid];
        rsg[h * SEQ + t0 + tid] = v;
    }
}

extern "C" void kernel_launch(void* const* d_in, const int* in_sizes, int n_in,
                              void* d_out, int out_size, void* d_ws, size_t ws_size,
                              hipStream_t stream) {
    (void)in_sizes; (void)n_in; (void)out_size;
    const float* qg = (const float*)d_in[0];
    const float* kg = (const float*)d_in[1];
    const float* vg = (const float*)d_in[2];
    float* outg = (float*)d_out;
    float* rsg  = outg + (size_t)HEADS * SEQ * DIM;

    const size_t nElem   = (size_t)HEADS * SEQ * DIM;        // 4.19M
    const size_t lseB    = (size_t)HEADS * SEQ * sizeof(float);
    const size_t needB   = lseB + 3 * nElem * sizeof(__bf16);

    if (ws_size >= needB) {
        float*  lseg = (float*)d_ws;
        __bf16* Qb = (__bf16*)((char*)d_ws + lseB);
        __bf16* Kb = Qb + nElem;
        __bf16* Vb = Kb + nElem;
        conv_fused_kernel<<<dim3(SEQ / 64, HEADS, 3), 256, 0, stream>>>(
            qg, kg, vg, Qb, Kb, Vb);
        fa_fwd8_kernel<<<dim3(512), 512, 0, stream>>>(Qb, Kb, Vb, outg, lseg);
        fa_colsum8_kernel<<<dim3(512), 512, 0, stream>>>(Qb, Kb, lseg, rsg);
    } else {
        float* lseg = (float*)d_ws;
        dim3 grid(SEQ / QT, HEADS);
        fa_fwd_v1_kernel<<<grid, 256, 0, stream>>>(qg, kg, vg, outg, lseg);
        fa_colsum_v1_kernel<<<grid, 256, 0, stream>>>(qg, kg, lseg, rsg);
    }
}